// Round 3
// baseline (1098.650 us; speedup 1.0000x reference)
//
#include <hip/hip_runtime.h>
#include <math.h>

// ---------------------------------------------------------------------------
// MultiStreamCNN: two conv streams (3->32->64 w/ relu+maxpool2), concat,
// fuse conv 3x3 (128->128) + relu + global mean, det 1x1 conv, sigmoid + NMS.
// All fp32 (no fp32-input MFMA on CDNA4; bf16 risks the binary `keep` output).
//
// R3: conv2/fuse use WAVE-PRIVATE LDS halos (18x18 per wave) -> zero barriers
// in the ic loop. Within-wave LDS write->read ordering is handled by lgkmcnt;
// waves slide freely so s_load / global-load latency is covered by sibling
// waves' FMA streams.
// ---------------------------------------------------------------------------

// ---------- Kernel A: conv3x3 (3->32) + bias + relu + maxpool2 --------------
// in x: (8,3,512,512), out: (8,32,256,256). Block = 16x16 pooled pixels.
__global__ __launch_bounds__(256) void conv1_pool(
    const float* __restrict__ x, const float* __restrict__ w,
    const float* __restrict__ bias, float* __restrict__ out)
{
    __shared__ float s[3 * 34 * 34];
    const int b = blockIdx.z;
    const int tileX = blockIdx.x, tileY = blockIdx.y;
    const int tid = threadIdx.x;
    const int tx = tid & 15, ty = tid >> 4;
    const int ih0 = tileY * 32 - 1, iw0 = tileX * 32 - 1;

    for (int i = tid; i < 3 * 34 * 34; i += 256) {
        int c = i / 1156, r = i % 1156;
        int y = r / 34, xx = r % 34;
        int ih = ih0 + y, iw = iw0 + xx;
        float v = 0.f;
        if (ih >= 0 && ih < 512 && iw >= 0 && iw < 512)
            v = x[((b * 3 + c) * 512 + ih) * 512 + iw];
        s[i] = v;
    }
    __syncthreads();

    float in[3][4][4];
#pragma unroll
    for (int c = 0; c < 3; ++c)
#pragma unroll
        for (int dy = 0; dy < 4; ++dy)
#pragma unroll
            for (int dx = 0; dx < 4; ++dx)
                in[c][dy][dx] = s[c * 1156 + (2 * ty + dy) * 34 + (2 * tx + dx)];

    const int oh = tileY * 16 + ty, ow = tileX * 16 + tx;
    for (int oc = 0; oc < 32; ++oc) {
        const float bv = bias[oc];
        float m = -INFINITY;
#pragma unroll
        for (int py = 0; py < 2; ++py)
#pragma unroll
            for (int px = 0; px < 2; ++px) {
                float a = 0.f;
#pragma unroll
                for (int c = 0; c < 3; ++c)
#pragma unroll
                    for (int ky = 0; ky < 3; ++ky)
#pragma unroll
                        for (int kx = 0; kx < 3; ++kx)
                            a = fmaf(w[((oc * 3 + c) * 3 + ky) * 3 + kx],
                                     in[c][py + ky][px + kx], a);
                m = fmaxf(m, a);
            }
        m = fmaxf(m + bv, 0.f);  // bias uniform over window; relu after max ok
        out[((b * 32 + oc) * 256 + oh) * 256 + ow] = m;
    }
}

// ---------- Kernel B: conv3x3 (32->64) + bias + relu + maxpool2 -------------
// in: (8,32,256,256), out: (8,64,128,128).
// Block = 4 waves; each wave owns a 16x16 conv-px subtile (2x2 px/lane) with
// its private 18x18 LDS halo. No barriers. 16 oc per block (z = b*4+ocg).
__global__ __launch_bounds__(256) void conv2_pool(
    const float* __restrict__ in, const float* __restrict__ w,
    const float* __restrict__ bias, float* __restrict__ out)
{
    __shared__ float sb[4][2][324];
    const int z = blockIdx.z, b = z >> 2, ocg = z & 3;
    const int tid = threadIdx.x;
    const int w_id = tid >> 6, lane = tid & 63;
    const int lx = lane & 7, ly = lane >> 3;
    const int wy0 = blockIdx.y * 32 + (w_id >> 1) * 16 - 1;  // halo origin
    const int wx0 = blockIdx.x * 32 + (w_id & 1) * 16 - 1;

    // wave-private staging slots (ic-invariant): i = lane + 64k over 18x18 halo
    int off_[6]; float msk_[6];
#pragma unroll
    for (int k = 0; k < 6; ++k) {
        int i = lane + k * 64;
        int y = i / 18, xx = i - y * 18;
        int ih = wy0 + y, iw = wx0 + xx;
        bool ok = (i < 324) & (ih >= 0) & (ih < 256) & (iw >= 0) & (iw < 256);
        off_[k] = ok ? ih * 256 + iw : 0;
        msk_[k] = ok ? 1.f : 0.f;
    }

    float r_[6];
    {
        const float* base = in + ((size_t)(b * 32) << 16);
#pragma unroll
        for (int k = 0; k < 6; ++k) r_[k] = base[off_[k]] * msk_[k];
    }

    float acc[16][2][2];
#pragma unroll
    for (int oc = 0; oc < 16; ++oc)
#pragma unroll
        for (int i = 0; i < 4; ++i) acc[oc][i >> 1][i & 1] = 0.f;

    for (int ic = 0; ic < 32; ++ic) {
        float* s = sb[w_id][ic & 1];
#pragma unroll
        for (int k = 0; k < 6; ++k) {
            int i = lane + k * 64;
            if (i < 324) s[i] = r_[k];
        }
        if (ic + 1 < 32) {  // prefetch next ic into regs; consumed next iter
            const float* nb = in + ((size_t)(b * 32 + ic + 1) << 16);
#pragma unroll
            for (int k = 0; k < 6; ++k) r_[k] = nb[off_[k]] * msk_[k];
        }
        float p[4][4];
#pragma unroll
        for (int dy = 0; dy < 4; ++dy)
#pragma unroll
            for (int dx = 0; dx < 4; ++dx)
                p[dy][dx] = s[(2 * ly + dy) * 18 + 2 * lx + dx];
        const float* wic = &w[((ocg * 16) * 32 + ic) * 9];
#pragma unroll
        for (int oc = 0; oc < 16; ++oc) {
            const float* wo = wic + oc * (32 * 9);
#pragma unroll
            for (int py = 0; py < 2; ++py)
#pragma unroll
                for (int px = 0; px < 2; ++px) {
                    float a = acc[oc][py][px];
#pragma unroll
                    for (int ky = 0; ky < 3; ++ky)
#pragma unroll
                        for (int kx = 0; kx < 3; ++kx)
                            a = fmaf(wo[ky * 3 + kx], p[py + ky][px + kx], a);
                    acc[oc][py][px] = a;
                }
        }
    }

    const int py = blockIdx.y * 16 + (w_id >> 1) * 8 + ly;
    const int px = blockIdx.x * 16 + (w_id & 1) * 8 + lx;
#pragma unroll
    for (int oc = 0; oc < 16; ++oc) {
        float bv = bias[ocg * 16 + oc];
        float m = fmaxf(fmaxf(acc[oc][0][0], acc[oc][0][1]),
                        fmaxf(acc[oc][1][0], acc[oc][1][1]));
        m = fmaxf(m + bv, 0.f);
        out[((size_t)(b * 64 + ocg * 16 + oc) * 128 + py) * 128 + px] = m;
    }
}

// ---------- Kernel C: fuse conv3x3 (128->128) + bias + relu + global mean ---
// in: s2_rgb (8,64,128,128) ++ s2_ir (8,64,128,128); out featsum: (8,128) sums.
// Same wave-private structure; one barrier total (final reduction).
__global__ __launch_bounds__(256) void fuse_mean(
    const float* __restrict__ inA, const float* __restrict__ inB,
    const float* __restrict__ w, const float* __restrict__ bias,
    float* __restrict__ featsum)
{
    __shared__ float sb[4][2][324];
    __shared__ float partial[4][16];
    const int z = blockIdx.z, b = z >> 3, ocg = z & 7;
    const int tid = threadIdx.x;
    const int w_id = tid >> 6, lane = tid & 63;
    const int lx = lane & 7, ly = lane >> 3;
    const int wy0 = blockIdx.y * 32 + (w_id >> 1) * 16 - 1;
    const int wx0 = blockIdx.x * 32 + (w_id & 1) * 16 - 1;

    int off_[6]; float msk_[6];
#pragma unroll
    for (int k = 0; k < 6; ++k) {
        int i = lane + k * 64;
        int y = i / 18, xx = i - y * 18;
        int ih = wy0 + y, iw = wx0 + xx;
        bool ok = (i < 324) & (ih >= 0) & (ih < 128) & (iw >= 0) & (iw < 128);
        off_[k] = ok ? ih * 128 + iw : 0;
        msk_[k] = ok ? 1.f : 0.f;
    }

    float r_[6];
    {
        const float* base = inA + ((size_t)(b * 64) << 14);
#pragma unroll
        for (int k = 0; k < 6; ++k) r_[k] = base[off_[k]] * msk_[k];
    }

    float acc[16][2][2];
#pragma unroll
    for (int oc = 0; oc < 16; ++oc)
#pragma unroll
        for (int i = 0; i < 4; ++i) acc[oc][i >> 1][i & 1] = 0.f;

    for (int ic = 0; ic < 128; ++ic) {
        float* s = sb[w_id][ic & 1];
#pragma unroll
        for (int k = 0; k < 6; ++k) {
            int i = lane + k * 64;
            if (i < 324) s[i] = r_[k];
        }
        if (ic + 1 < 128) {
            int icn = ic + 1;
            const float* nb = (icn < 64)
                ? inA + ((size_t)(b * 64 + icn) << 14)
                : inB + ((size_t)(b * 64 + icn - 64) << 14);
#pragma unroll
            for (int k = 0; k < 6; ++k) r_[k] = nb[off_[k]] * msk_[k];
        }
        float p[4][4];
#pragma unroll
        for (int dy = 0; dy < 4; ++dy)
#pragma unroll
            for (int dx = 0; dx < 4; ++dx)
                p[dy][dx] = s[(2 * ly + dy) * 18 + 2 * lx + dx];
        const float* wic = &w[((ocg * 16) * 128 + ic) * 9];
#pragma unroll
        for (int oc = 0; oc < 16; ++oc) {
            const float* wo = wic + oc * (128 * 9);
#pragma unroll
            for (int py = 0; py < 2; ++py)
#pragma unroll
                for (int px = 0; px < 2; ++px) {
                    float a = acc[oc][py][px];
#pragma unroll
                    for (int ky = 0; ky < 3; ++ky)
#pragma unroll
                        for (int kx = 0; kx < 3; ++kx)
                            a = fmaf(wo[ky * 3 + kx], p[py + ky][px + kx], a);
                    acc[oc][py][px] = a;
                }
        }
    }

    // bias + relu + reduce over this block's 32x32 px
#pragma unroll
    for (int oc = 0; oc < 16; ++oc) {
        float bv = bias[ocg * 16 + oc];
        float v = fmaxf(acc[oc][0][0] + bv, 0.f) + fmaxf(acc[oc][0][1] + bv, 0.f)
                + fmaxf(acc[oc][1][0] + bv, 0.f) + fmaxf(acc[oc][1][1] + bv, 0.f);
        v += __shfl_xor(v, 1);
        v += __shfl_xor(v, 2);
        v += __shfl_xor(v, 4);
        v += __shfl_xor(v, 8);
        v += __shfl_xor(v, 16);
        v += __shfl_xor(v, 32);
        if (lane == 0) partial[w_id][oc] = v;
    }
    __syncthreads();
    if (tid < 16) {
        float v = partial[0][tid] + partial[1][tid] + partial[2][tid] + partial[3][tid];
        atomicAdd(&featsum[b * 128 + ocg * 16 + tid], v);
    }
}

// ---------- Kernel D: det head + sigmoid + NMS + outputs --------------------
__global__ void det_nms(const float* __restrict__ featsum,
                        const float* __restrict__ dw, const float* __restrict__ db,
                        float* __restrict__ out)
{
    const int b = threadIdx.x;
    if (b >= 8) return;
    const float inv = 1.0f / 16384.0f;

    float p[18];
    for (int j = 0; j < 18; ++j) {
        float a = db[j];
        const float* wp = &dw[j * 128];
        const float* f = &featsum[b * 128];
        for (int c = 0; c < 128; ++c) a = fmaf(wp[c], f[c] * inv, a);
        p[j] = a;
    }
    for (int a = 0; a < 3; ++a)
        for (int e = 0; e < 6; ++e) out[b * 18 + a * 6 + e] = p[a * 6 + e];

    float bx[3][4], sc[3];
    bool ck[3];
    for (int a = 0; a < 3; ++a) {
        for (int k = 0; k < 4; ++k) {
            bx[a][k] = p[a * 6 + k];
            out[144 + b * 12 + a * 4 + k] = bx[a][k];
        }
        float sg = 1.f / (1.f + expf(-p[a * 6 + 4]));
        sc[a] = sg;
        ck[a] = sg > 0.5f;
        out[240 + b * 3 + a] = sg;
    }

    float key[3];
    int order[3];
    bool used[3] = {false, false, false};
    for (int a = 0; a < 3; ++a) key[a] = ck[a] ? sc[a] : -INFINITY;
    for (int i = 0; i < 3; ++i) {
        int best = -1;
        float bk = 0.f;
        for (int a = 0; a < 3; ++a) {
            if (used[a]) continue;
            if (best < 0 || key[a] > bk) { best = a; bk = key[a]; }
        }
        order[i] = best;
        used[best] = true;
    }

    float X1[3], Y1[3], X2[3], Y2[3], AR[3];
    for (int i = 0; i < 3; ++i) {
        int o = order[i];
        X1[i] = bx[o][0]; Y1[i] = bx[o][1];
        X2[i] = bx[o][2]; Y2[i] = bx[o][3];
        AR[i] = (X2[i] - X1[i]) * (Y2[i] - Y1[i]);
    }
    bool suppressed[3] = {false, false, false}, keep_s[3];
    for (int i = 0; i < 3; ++i) {
        bool valid = !suppressed[i];
        keep_s[i] = valid;
        if (valid) {
            for (int j = i + 1; j < 3; ++j) {
                float ix1 = fmaxf(X1[i], X1[j]), iy1 = fmaxf(Y1[i], Y1[j]);
                float ix2 = fminf(X2[i], X2[j]), iy2 = fminf(Y2[i], Y2[j]);
                float inter = fmaxf(ix2 - ix1, 0.f) * fmaxf(iy2 - iy1, 0.f);
                float iou = inter / (AR[i] + AR[j] - inter);
                if (iou > 0.5f) suppressed[j] = true;  // NaN compares false, like jnp
            }
        }
    }
    bool keep[3];
    for (int i = 0; i < 3; ++i) keep[order[i]] = keep_s[i];
    for (int a = 0; a < 3; ++a)
        out[264 + b * 3 + a] = (keep[a] && ck[a]) ? 1.f : 0.f;
}

__global__ void zero_feat(float* __restrict__ p)
{
    int i = blockIdx.x * 256 + threadIdx.x;
    if (i < 1024) p[i] = 0.f;
}

// ---------------------------------------------------------------------------
extern "C" void kernel_launch(void* const* d_in, const int* in_sizes, int n_in,
                              void* d_out, int out_size, void* d_ws, size_t ws_size,
                              hipStream_t stream)
{
    const float* x      = (const float*)d_in[0];
    const float* rgb_w1 = (const float*)d_in[1];
    const float* rgb_b1 = (const float*)d_in[2];
    const float* rgb_w2 = (const float*)d_in[3];
    const float* rgb_b2 = (const float*)d_in[4];
    const float* ir_w1  = (const float*)d_in[5];
    const float* ir_b1  = (const float*)d_in[6];
    const float* ir_w2  = (const float*)d_in[7];
    const float* ir_b2  = (const float*)d_in[8];
    const float* fuse_w = (const float*)d_in[9];
    const float* fuse_b = (const float*)d_in[10];
    const float* det_w  = (const float*)d_in[11];
    const float* det_b  = (const float*)d_in[12];
    float* out = (float*)d_out;

    char* ws = (char*)d_ws;
    float* s1   = (float*)(ws);                               // 67,108,864 B
    float* s2r  = (float*)(ws + 67108864);                    // 33,554,432 B
    float* s2i  = (float*)(ws + 67108864 + 33554432);         // 33,554,432 B
    float* feat = (float*)(ws + 67108864 + 2 * 33554432);     // 4,096 B

    dim3 blk(256);
    hipLaunchKernelGGL(zero_feat, dim3(4), blk, 0, stream, feat);
    // s1 reused between streams (serialized on the stream)
    hipLaunchKernelGGL(conv1_pool, dim3(16, 16, 8), blk, 0, stream, x, rgb_w1, rgb_b1, s1);
    hipLaunchKernelGGL(conv2_pool, dim3(8, 8, 32), blk, 0, stream, s1, rgb_w2, rgb_b2, s2r);
    hipLaunchKernelGGL(conv1_pool, dim3(16, 16, 8), blk, 0, stream, x, ir_w1, ir_b1, s1);
    hipLaunchKernelGGL(conv2_pool, dim3(8, 8, 32), blk, 0, stream, s1, ir_w2, ir_b2, s2i);
    hipLaunchKernelGGL(fuse_mean, dim3(4, 4, 64), blk, 0, stream, s2r, s2i, fuse_w, fuse_b, feat);
    hipLaunchKernelGGL(det_nms, dim3(1), dim3(64), 0, stream, feat, det_w, det_b, out);
}

// Round 4
// 842.832 us; speedup vs baseline: 1.3035x; 1.3035x over previous
//
#include <hip/hip_runtime.h>
#include <math.h>

// ---------------------------------------------------------------------------
// MultiStreamCNN. R4: fuse conv (128ic x 3x3 x 128oc, the dominant cost) moved
// to split-bf16 MFMA (D = AhiBhi + AhiBlo + AloBhi, ~2^-16 rel error).
// conv2 writes its output directly as NHWC bf16 hi/lo (fragment-friendly).
// conv1/conv2 bodies are the proven R2 versions (R3 wave-private LDS regressed:
// 4-way bank conflicts + lgkmcnt serialization).
// ---------------------------------------------------------------------------

typedef __bf16 bf16x8 __attribute__((ext_vector_type(8)));
typedef float f32x4 __attribute__((ext_vector_type(4)));

static __device__ __forceinline__ ushort f2bf(float f) {
    unsigned u = __float_as_uint(f);
    unsigned r = (u + 0x7fffu + ((u >> 16) & 1u)) >> 16;   // RNE
    return (ushort)r;
}
static __device__ __forceinline__ float bf2f(ushort h) {
    return __uint_as_float(((unsigned)h) << 16);
}

// ---------- Kernel A: conv3x3 (3->32) + bias + relu + maxpool2 --------------
__global__ __launch_bounds__(256) void conv1_pool(
    const float* __restrict__ x, const float* __restrict__ w,
    const float* __restrict__ bias, float* __restrict__ out)
{
    __shared__ float s[3 * 34 * 34];
    const int b = blockIdx.z;
    const int tileX = blockIdx.x, tileY = blockIdx.y;
    const int tid = threadIdx.x;
    const int tx = tid & 15, ty = tid >> 4;
    const int ih0 = tileY * 32 - 1, iw0 = tileX * 32 - 1;

    for (int i = tid; i < 3 * 34 * 34; i += 256) {
        int c = i / 1156, r = i % 1156;
        int y = r / 34, xx = r % 34;
        int ih = ih0 + y, iw = iw0 + xx;
        float v = 0.f;
        if (ih >= 0 && ih < 512 && iw >= 0 && iw < 512)
            v = x[((b * 3 + c) * 512 + ih) * 512 + iw];
        s[i] = v;
    }
    __syncthreads();

    float in[3][4][4];
#pragma unroll
    for (int c = 0; c < 3; ++c)
#pragma unroll
        for (int dy = 0; dy < 4; ++dy)
#pragma unroll
            for (int dx = 0; dx < 4; ++dx)
                in[c][dy][dx] = s[c * 1156 + (2 * ty + dy) * 34 + (2 * tx + dx)];

    const int oh = tileY * 16 + ty, ow = tileX * 16 + tx;
    for (int oc = 0; oc < 32; ++oc) {
        const float bv = bias[oc];
        float m = -INFINITY;
#pragma unroll
        for (int py = 0; py < 2; ++py)
#pragma unroll
            for (int px = 0; px < 2; ++px) {
                float a = 0.f;
#pragma unroll
                for (int c = 0; c < 3; ++c)
#pragma unroll
                    for (int ky = 0; ky < 3; ++ky)
#pragma unroll
                        for (int kx = 0; kx < 3; ++kx)
                            a = fmaf(w[((oc * 3 + c) * 3 + ky) * 3 + kx],
                                     in[c][py + ky][px + kx], a);
                m = fmaxf(m, a);
            }
        m = fmaxf(m + bv, 0.f);
        out[((b * 32 + oc) * 256 + oh) * 256 + ow] = m;
    }
}

// ---------- Kernel B: conv3x3 (32->64) + bias + relu + maxpool2 -------------
// out: NHWC bf16 split buffers Ahi/Alo, layout ((b*128+y)*128+x)*128 + ch,
// ch = stream_base + ocg*16 + oc (16 consecutive channels per thread = 32B).
__global__ __launch_bounds__(256) void conv2_pool(
    const float* __restrict__ in, const float* __restrict__ w,
    const float* __restrict__ bias, ushort* __restrict__ Ahi,
    ushort* __restrict__ Alo, int stream_base)
{
    __shared__ float sb[2][34 * 34];
    const int z = blockIdx.z, b = z >> 2, ocg = z & 3;
    const int tid = threadIdx.x, tx = tid & 15, ty = tid >> 4;
    const int cy0 = blockIdx.y * 32 - 1, cx0 = blockIdx.x * 32 - 1;

    int off_[5]; float msk_[5];
#pragma unroll
    for (int k = 0; k < 5; ++k) {
        int i = tid + k * 256;
        int y = i / 34, xx = i - y * 34;
        int ih = cy0 + y, iw = cx0 + xx;
        bool ok = (i < 1156) & (ih >= 0) & (ih < 256) & (iw >= 0) & (iw < 256);
        off_[k] = ok ? ih * 256 + iw : 0;
        msk_[k] = ok ? 1.f : 0.f;
    }

    float r_[5];
    {
        const float* base = in + ((size_t)(b * 32) << 16);
#pragma unroll
        for (int k = 0; k < 5; ++k) r_[k] = base[off_[k]] * msk_[k];
    }

    float acc[16][2][2];
#pragma unroll
    for (int oc = 0; oc < 16; ++oc)
#pragma unroll
        for (int i = 0; i < 4; ++i) acc[oc][i >> 1][i & 1] = 0.f;

    for (int ic = 0; ic < 32; ++ic) {
        float* s = sb[ic & 1];
#pragma unroll
        for (int k = 0; k < 5; ++k) {
            int i = tid + k * 256;
            if (i < 1156) s[i] = r_[k];
        }
        __syncthreads();
        if (ic + 1 < 32) {
            const float* nb = in + ((size_t)(b * 32 + ic + 1) << 16);
#pragma unroll
            for (int k = 0; k < 5; ++k) r_[k] = nb[off_[k]] * msk_[k];
        }
        float p[4][4];
#pragma unroll
        for (int dy = 0; dy < 4; ++dy)
#pragma unroll
            for (int dx = 0; dx < 4; ++dx)
                p[dy][dx] = s[(2 * ty + dy) * 34 + 2 * tx + dx];
        const float* wic = &w[((ocg * 16) * 32 + ic) * 9];
#pragma unroll
        for (int oc = 0; oc < 16; ++oc) {
            const float* wo = wic + oc * (32 * 9);
#pragma unroll
            for (int py = 0; py < 2; ++py)
#pragma unroll
                for (int px = 0; px < 2; ++px) {
                    float a = acc[oc][py][px];
#pragma unroll
                    for (int ky = 0; ky < 3; ++ky)
#pragma unroll
                        for (int kx = 0; kx < 3; ++kx)
                            a = fmaf(wo[ky * 3 + kx], p[py + ky][px + kx], a);
                    acc[oc][py][px] = a;
                }
        }
    }

    const int pooly = blockIdx.y * 16 + ty, poolx = blockIdx.x * 16 + tx;
    __attribute__((aligned(16))) ushort hb[16];
    __attribute__((aligned(16))) ushort lb[16];
#pragma unroll
    for (int oc = 0; oc < 16; ++oc) {
        float bv = bias[ocg * 16 + oc];
        float m = fmaxf(fmaxf(acc[oc][0][0], acc[oc][0][1]),
                        fmaxf(acc[oc][1][0], acc[oc][1][1]));
        m = fmaxf(m + bv, 0.f);
        ushort h = f2bf(m);
        hb[oc] = h;
        lb[oc] = f2bf(m - bf2f(h));
    }
    size_t base = ((size_t)(b * 128 + pooly) * 128 + poolx) * 128
                + stream_base + ocg * 16;
    uint4* dh = (uint4*)(Ahi + base);
    uint4* dl = (uint4*)(Alo + base);
    dh[0] = *(const uint4*)&hb[0];
    dh[1] = *(const uint4*)&hb[8];
    dl[0] = *(const uint4*)&lb[0];
    dl[1] = *(const uint4*)&lb[8];
}

// ---------- wprep: fuse_w fp32 -> fragment-ordered bf16 hi/lo ---------------
// Wf[t][chunk][oc][kk] = W[oc][ic=chunk*32+kk][ky=t/3][kx=t%3]
__global__ __launch_bounds__(256) void wprep(
    const float* __restrict__ fw, ushort* __restrict__ Whi,
    ushort* __restrict__ Wlo)
{
    int idx = blockIdx.x * 256 + threadIdx.x;
    if (idx >= 147456) return;
    int t = idx >> 14;            // /16384
    int c = (idx >> 12) & 3;
    int oc = (idx >> 5) & 127;
    int kk = idx & 31;
    int ic = c * 32 + kk;
    int ky = t / 3, kx = t - ky * 3;
    float v = fw[((oc * 128 + ic) * 3 + ky) * 3 + kx];
    ushort h = f2bf(v);
    Whi[idx] = h;
    Wlo[idx] = f2bf(v - bf2f(h));
}

// ---------- Kernel C: fuse conv via split-bf16 MFMA + relu + global mean ----
// Block: 64 px (one row segment) x 128 oc; 4 waves, each 16px x 128oc.
// K-loop: 9 taps x 4 ic-chunks of 32; D += AhiBhi + AhiBlo + AloBhi.
__global__ __launch_bounds__(256) void fuse_mfma(
    const ushort* __restrict__ Ahi, const ushort* __restrict__ Alo,
    const ushort* __restrict__ Whi, const ushort* __restrict__ Wlo,
    const float* __restrict__ bias, float* __restrict__ featsum)
{
    __shared__ ushort ldsB[2][2][4096];   // [parity][hi/lo][32k x 128oc]
    __shared__ float partial[4][128];
    const int seg = blockIdx.x, y = blockIdx.y, b = blockIdx.z;
    const int tid = threadIdx.x, wsub = tid >> 6, lane = tid & 63;
    const int n = lane & 15, q = lane >> 4;   // n: M-row (A) / N-col (B,D)
    const int x0 = seg * 64 + wsub * 16;

    f32x4 acc[8];
#pragma unroll
    for (int g = 0; g < 8; ++g) acc[g] = (f32x4){0.f, 0.f, 0.f, 0.f};

    const uint4 zero4 = make_uint4(0u, 0u, 0u, 0u);
    uint4 pAh = zero4, pAl = zero4;

    // A-frag loader for flat tap-chunk index tc
    auto loadA = [&](int tc, uint4& oh, uint4& ol) {
        int t = tc >> 2, c = tc & 3;
        int ky = t / 3, kx = t - ky * 3;
        int yy = y + ky - 1;
        int xp = x0 + n + kx - 1;
        bool ok = (yy >= 0) & (yy < 128) & (xp >= 0) & (xp < 128);
        int yyc = ok ? yy : 0, xpc = ok ? xp : 0;
        size_t aoff = ((size_t)((b * 128 + yyc) * 128 + xpc) << 7) + c * 32 + q * 8;
        oh = ok ? *(const uint4*)(Ahi + aoff) : zero4;
        ol = ok ? *(const uint4*)(Alo + aoff) : zero4;
    };
    // B stager: 16KB (hi+lo) for tap-chunk tc into parity buffer
    auto stageB = [&](int tc, int par) {
        int gbase = tc * 4096 + tid * 16;
        const uint4* gh = (const uint4*)(Whi + gbase);
        const uint4* gl = (const uint4*)(Wlo + gbase);
        uint4* dh = (uint4*)&ldsB[par][0][tid * 16];
        uint4* dl = (uint4*)&ldsB[par][1][tid * 16];
        dh[0] = gh[0]; dh[1] = gh[1];
        dl[0] = gl[0]; dl[1] = gl[1];
    };

    loadA(0, pAh, pAl);
    stageB(0, 0);

    for (int tc = 0; tc < 36; ++tc) {
        const int par = tc & 1;
        __syncthreads();   // B(par) staged; prior reads of buffer par drained
        uint4 cAh = pAh, cAl = pAl;
        if (tc + 1 < 36) {
            loadA(tc + 1, pAh, pAl);
            stageB(tc + 1, par ^ 1);
        }
        bf16x8 ah = __builtin_bit_cast(bf16x8, cAh);
        bf16x8 al = __builtin_bit_cast(bf16x8, cAl);
#pragma unroll
        for (int g = 0; g < 8; ++g) {
            const uint4* bh4 = (const uint4*)&ldsB[par][0][(g * 16 + n) * 32 + q * 8];
            const uint4* bl4 = (const uint4*)&ldsB[par][1][(g * 16 + n) * 32 + q * 8];
            bf16x8 bh = __builtin_bit_cast(bf16x8, *bh4);
            bf16x8 bl = __builtin_bit_cast(bf16x8, *bl4);
            acc[g] = __builtin_amdgcn_mfma_f32_16x16x32_bf16(ah, bh, acc[g], 0, 0, 0);
            acc[g] = __builtin_amdgcn_mfma_f32_16x16x32_bf16(ah, bl, acc[g], 0, 0, 0);
            acc[g] = __builtin_amdgcn_mfma_f32_16x16x32_bf16(al, bh, acc[g], 0, 0, 0);
        }
    }

    // Epilogue: D[row px = q*4+r][col oc = n]; bias+relu, sum over px.
#pragma unroll
    for (int g = 0; g < 8; ++g) {
        float bv = bias[g * 16 + n];
        float v = 0.f;
#pragma unroll
        for (int r = 0; r < 4; ++r) v += fmaxf(acc[g][r] + bv, 0.f);
        v += __shfl_xor(v, 16);
        v += __shfl_xor(v, 32);
        if (lane < 16) partial[wsub][g * 16 + lane] = v;
    }
    __syncthreads();
    if (tid < 128) {
        float v = partial[0][tid] + partial[1][tid] + partial[2][tid] + partial[3][tid];
        atomicAdd(&featsum[b * 128 + tid], v);
    }
}

// ---------- Kernel D: det head + sigmoid + NMS + outputs --------------------
__global__ void det_nms(const float* __restrict__ featsum,
                        const float* __restrict__ dw, const float* __restrict__ db,
                        float* __restrict__ out)
{
    const int b = threadIdx.x;
    if (b >= 8) return;
    const float inv = 1.0f / 16384.0f;

    float p[18];
    for (int j = 0; j < 18; ++j) {
        float a = db[j];
        const float* wp = &dw[j * 128];
        const float* f = &featsum[b * 128];
        for (int c = 0; c < 128; ++c) a = fmaf(wp[c], f[c] * inv, a);
        p[j] = a;
    }
    for (int a = 0; a < 3; ++a)
        for (int e = 0; e < 6; ++e) out[b * 18 + a * 6 + e] = p[a * 6 + e];

    float bx[3][4], sc[3];
    bool ck[3];
    for (int a = 0; a < 3; ++a) {
        for (int k = 0; k < 4; ++k) {
            bx[a][k] = p[a * 6 + k];
            out[144 + b * 12 + a * 4 + k] = bx[a][k];
        }
        float sg = 1.f / (1.f + expf(-p[a * 6 + 4]));
        sc[a] = sg;
        ck[a] = sg > 0.5f;
        out[240 + b * 3 + a] = sg;
    }

    float key[3];
    int order[3];
    bool used[3] = {false, false, false};
    for (int a = 0; a < 3; ++a) key[a] = ck[a] ? sc[a] : -INFINITY;
    for (int i = 0; i < 3; ++i) {
        int best = -1;
        float bk = 0.f;
        for (int a = 0; a < 3; ++a) {
            if (used[a]) continue;
            if (best < 0 || key[a] > bk) { best = a; bk = key[a]; }
        }
        order[i] = best;
        used[best] = true;
    }

    float X1[3], Y1[3], X2[3], Y2[3], AR[3];
    for (int i = 0; i < 3; ++i) {
        int o = order[i];
        X1[i] = bx[o][0]; Y1[i] = bx[o][1];
        X2[i] = bx[o][2]; Y2[i] = bx[o][3];
        AR[i] = (X2[i] - X1[i]) * (Y2[i] - Y1[i]);
    }
    bool suppressed[3] = {false, false, false}, keep_s[3];
    for (int i = 0; i < 3; ++i) {
        bool valid = !suppressed[i];
        keep_s[i] = valid;
        if (valid) {
            for (int j = i + 1; j < 3; ++j) {
                float ix1 = fmaxf(X1[i], X1[j]), iy1 = fmaxf(Y1[i], Y1[j]);
                float ix2 = fminf(X2[i], X2[j]), iy2 = fminf(Y2[i], Y2[j]);
                float inter = fmaxf(ix2 - ix1, 0.f) * fmaxf(iy2 - iy1, 0.f);
                float iou = inter / (AR[i] + AR[j] - inter);
                if (iou > 0.5f) suppressed[j] = true;
            }
        }
    }
    bool keep[3];
    for (int i = 0; i < 3; ++i) keep[order[i]] = keep_s[i];
    for (int a = 0; a < 3; ++a)
        out[264 + b * 3 + a] = (keep[a] && ck[a]) ? 1.f : 0.f;
}

__global__ void zero_feat(float* __restrict__ p)
{
    int i = blockIdx.x * 256 + threadIdx.x;
    if (i < 1024) p[i] = 0.f;
}

// ---------------------------------------------------------------------------
extern "C" void kernel_launch(void* const* d_in, const int* in_sizes, int n_in,
                              void* d_out, int out_size, void* d_ws, size_t ws_size,
                              hipStream_t stream)
{
    const float* x      = (const float*)d_in[0];
    const float* rgb_w1 = (const float*)d_in[1];
    const float* rgb_b1 = (const float*)d_in[2];
    const float* rgb_w2 = (const float*)d_in[3];
    const float* rgb_b2 = (const float*)d_in[4];
    const float* ir_w1  = (const float*)d_in[5];
    const float* ir_b1  = (const float*)d_in[6];
    const float* ir_w2  = (const float*)d_in[7];
    const float* ir_b2  = (const float*)d_in[8];
    const float* fuse_w = (const float*)d_in[9];
    const float* fuse_b = (const float*)d_in[10];
    const float* det_w  = (const float*)d_in[11];
    const float* det_b  = (const float*)d_in[12];
    float* out = (float*)d_out;

    char* ws = (char*)d_ws;
    // s1 (fp32 conv1 out) occupies [0, 67MB) during conv1/conv2; Wsplit +
    // featsum reuse that region afterwards (stream-ordered, safe).
    float*  s1   = (float*)(ws);                          // 67,108,864 B
    ushort* Whi  = (ushort*)(ws);                         // 294,912 B (post-conv2)
    ushort* Wlo  = (ushort*)(ws + 294912);                // 294,912 B
    float*  feat = (float*)(ws + 589824);                 // 4,096 B
    ushort* Ahi  = (ushort*)(ws + 67108864);              // 33,554,432 B
    ushort* Alo  = (ushort*)(ws + 100663296);             // 33,554,432 B

    dim3 blk(256);
    hipLaunchKernelGGL(conv1_pool, dim3(16, 16, 8), blk, 0, stream, x, rgb_w1, rgb_b1, s1);
    hipLaunchKernelGGL(conv2_pool, dim3(8, 8, 32), blk, 0, stream, s1, rgb_w2, rgb_b2, Ahi, Alo, 0);
    hipLaunchKernelGGL(conv1_pool, dim3(16, 16, 8), blk, 0, stream, x, ir_w1, ir_b1, s1);
    hipLaunchKernelGGL(conv2_pool, dim3(8, 8, 32), blk, 0, stream, s1, ir_w2, ir_b2, Ahi, Alo, 64);
    // s1 now dead: safe to overwrite its region with Wsplit/featsum
    hipLaunchKernelGGL(wprep, dim3(576), blk, 0, stream, fuse_w, Whi, Wlo);
    hipLaunchKernelGGL(zero_feat, dim3(4), blk, 0, stream, feat);
    hipLaunchKernelGGL(fuse_mfma, dim3(2, 128, 8), blk, 0, stream, Ahi, Alo, Whi, Wlo, fuse_b, feat);
    hipLaunchKernelGGL(det_nms, dim3(1), dim3(64), 0, stream, feat, det_w, det_b, out);
}

// Round 5
// 759.316 us; speedup vs baseline: 1.4469x; 1.1100x over previous
//
#include <hip/hip_runtime.h>
#include <math.h>

// ---------------------------------------------------------------------------
// MultiStreamCNN. R5: conv2 moved to split-bf16 MFMA (same scheme as fuse:
// D = AhiBhi + AhiBlo + AloBhi). conv1 emits NHWC bf16 hi/lo; conv2_mfma
// pools 2x2 (x-pairs in-register from adjacent D rows, y-pairs via LDS) and
// emits the NHWC hi/lo fuse input. fuse/det unchanged from R4 (absmax 0.0).
// ---------------------------------------------------------------------------

typedef __bf16 bf16x8 __attribute__((ext_vector_type(8)));
typedef float f32x4 __attribute__((ext_vector_type(4)));

static __device__ __forceinline__ ushort f2bf(float f) {
    unsigned u = __float_as_uint(f);
    unsigned r = (u + 0x7fffu + ((u >> 16) & 1u)) >> 16;   // RNE
    return (ushort)r;
}
static __device__ __forceinline__ float bf2f(ushort h) {
    return __uint_as_float(((unsigned)h) << 16);
}

// ---------- Kernel A: conv3x3 (3->32) + bias + relu + maxpool2 --------------
// in x: (8,3,512,512); out: NHWC bf16 hi/lo ((b*256+y)*256+x)*32 + oc.
__global__ __launch_bounds__(256) void conv1_pool(
    const float* __restrict__ x, const float* __restrict__ w,
    const float* __restrict__ bias, ushort* __restrict__ C1h,
    ushort* __restrict__ C1l)
{
    __shared__ float s[3 * 34 * 34];
    const int b = blockIdx.z;
    const int tileX = blockIdx.x, tileY = blockIdx.y;
    const int tid = threadIdx.x;
    const int tx = tid & 15, ty = tid >> 4;
    const int ih0 = tileY * 32 - 1, iw0 = tileX * 32 - 1;

    for (int i = tid; i < 3 * 34 * 34; i += 256) {
        int c = i / 1156, r = i % 1156;
        int y = r / 34, xx = r % 34;
        int ih = ih0 + y, iw = iw0 + xx;
        float v = 0.f;
        if (ih >= 0 && ih < 512 && iw >= 0 && iw < 512)
            v = x[((b * 3 + c) * 512 + ih) * 512 + iw];
        s[i] = v;
    }
    __syncthreads();

    float in[3][4][4];
#pragma unroll
    for (int c = 0; c < 3; ++c)
#pragma unroll
        for (int dy = 0; dy < 4; ++dy)
#pragma unroll
            for (int dx = 0; dx < 4; ++dx)
                in[c][dy][dx] = s[c * 1156 + (2 * ty + dy) * 34 + (2 * tx + dx)];

    const int oh = tileY * 16 + ty, ow = tileX * 16 + tx;
    __attribute__((aligned(16))) ushort hb[32];
    __attribute__((aligned(16))) ushort lb[32];
    for (int oc = 0; oc < 32; ++oc) {
        const float bv = bias[oc];
        float m = -INFINITY;
#pragma unroll
        for (int py = 0; py < 2; ++py)
#pragma unroll
            for (int px = 0; px < 2; ++px) {
                float a = 0.f;
#pragma unroll
                for (int c = 0; c < 3; ++c)
#pragma unroll
                    for (int ky = 0; ky < 3; ++ky)
#pragma unroll
                        for (int kx = 0; kx < 3; ++kx)
                            a = fmaf(w[((oc * 3 + c) * 3 + ky) * 3 + kx],
                                     in[c][py + ky][px + kx], a);
                m = fmaxf(m, a);
            }
        m = fmaxf(m + bv, 0.f);
        ushort h = f2bf(m);
        hb[oc] = h;
        lb[oc] = f2bf(m - bf2f(h));
    }
    size_t base = ((size_t)((b * 256 + oh) * 256 + ow)) << 5;
    uint4* dh = (uint4*)(C1h + base);
    uint4* dl = (uint4*)(C1l + base);
#pragma unroll
    for (int k = 0; k < 4; ++k) {
        dh[k] = *(const uint4*)&hb[k * 8];
        dl[k] = *(const uint4*)&lb[k * 8];
    }
}

// ---------- Kernel B: conv2 as split-bf16 MFMA + maxpool2 -------------------
// in: C1 NHWC hi/lo (8,256,256,32); w2 (64,32,3,3) fp32; out: A NHWC hi/lo
// (8,128,128,128ch) at stream_base. Block: pooled row Y, 64 pooled x.
// 4 waves: wave = (xhalf = wsub>>1, ypar = wsub&1); 4 M-tiles x 4 N-tiles.
__global__ __launch_bounds__(256) void conv2_mfma(
    const ushort* __restrict__ C1h, const ushort* __restrict__ C1l,
    const float* __restrict__ w2, const float* __restrict__ bias,
    ushort* __restrict__ Ahi, ushort* __restrict__ Alo, int stream_base)
{
    __shared__ ushort Bh[2][2048];   // [parity][oc*32+ic]
    __shared__ ushort Bl[2][2048];
    __shared__ float pool[4][32][64];  // [wsub][poolx_local][oc]
    const int seg = blockIdx.x, Y = blockIdx.y, b = blockIdx.z;
    const int tid = threadIdx.x, wsub = tid >> 6, lane = tid & 63;
    const int n = lane & 15, q = lane >> 4;
    const int yc = 2 * Y + (wsub & 1);              // conv row in [0,256)
    const int wx0 = seg * 128 + (wsub >> 1) * 64;   // conv x base for wave

    const uint4 zero4 = make_uint4(0u, 0u, 0u, 0u);

    // per-thread weight slice: oc = tid>>2, ic [icb, icb+8)
    const int woc = tid >> 2, wicb = (tid & 3) * 8;

    auto loadW = [&](int t, float* wr) {
#pragma unroll
        for (int e = 0; e < 8; ++e)
            wr[e] = w2[(woc * 32 + wicb + e) * 9 + t];
    };
    auto loadA = [&](int t, uint4* aH, uint4* aL) {
        int ky = t / 3, kx = t - ky * 3;
        int yy = yc + ky - 1;
        bool yok = (yy >= 0) & (yy < 256);
#pragma unroll
        for (int mt = 0; mt < 4; ++mt) {
            int xp = wx0 + mt * 16 + n + kx - 1;
            bool ok = yok & (xp >= 0) & (xp < 256);
            int yyc = ok ? yy : 0, xpc = ok ? xp : 0;
            size_t off = (((size_t)((b * 256 + yyc) * 256 + xpc)) << 5) + q * 8;
            aH[mt] = ok ? *(const uint4*)(C1h + off) : zero4;
            aL[mt] = ok ? *(const uint4*)(C1l + off) : zero4;
        }
    };

    f32x4 acc[4][4];
#pragma unroll
    for (int mt = 0; mt < 4; ++mt)
#pragma unroll
        for (int nt = 0; nt < 4; ++nt) acc[mt][nt] = (f32x4){0.f, 0.f, 0.f, 0.f};

    float wr[8];
    uint4 aH[4], aL[4];
    loadW(0, wr);
    loadA(0, aH, aL);

    for (int t = 0; t < 9; ++t) {
        const int par = t & 1;
        // stage this tap's weights (from prefetched regs) into LDS, split
        __attribute__((aligned(16))) ushort hb8[8], lb8[8];
#pragma unroll
        for (int e = 0; e < 8; ++e) {
            ushort h = f2bf(wr[e]);
            hb8[e] = h;
            lb8[e] = f2bf(wr[e] - bf2f(h));
        }
        *(uint4*)&Bh[par][tid * 8] = *(const uint4*)&hb8[0];
        *(uint4*)&Bl[par][tid * 8] = *(const uint4*)&lb8[0];
        __syncthreads();
        uint4 cH[4], cL[4];
#pragma unroll
        for (int mt = 0; mt < 4; ++mt) { cH[mt] = aH[mt]; cL[mt] = aL[mt]; }
        if (t + 1 < 9) {
            loadW(t + 1, wr);
            loadA(t + 1, aH, aL);
        }
        bf16x8 bh[4], bl[4];
#pragma unroll
        for (int nt = 0; nt < 4; ++nt) {
            int oc = nt * 16 + n;
            bh[nt] = __builtin_bit_cast(bf16x8, *(const uint4*)&Bh[par][oc * 32 + q * 8]);
            bl[nt] = __builtin_bit_cast(bf16x8, *(const uint4*)&Bl[par][oc * 32 + q * 8]);
        }
#pragma unroll
        for (int mt = 0; mt < 4; ++mt) {
            bf16x8 ah = __builtin_bit_cast(bf16x8, cH[mt]);
            bf16x8 al = __builtin_bit_cast(bf16x8, cL[mt]);
#pragma unroll
            for (int nt = 0; nt < 4; ++nt) {
                acc[mt][nt] = __builtin_amdgcn_mfma_f32_16x16x32_bf16(ah, bh[nt], acc[mt][nt], 0, 0, 0);
                acc[mt][nt] = __builtin_amdgcn_mfma_f32_16x16x32_bf16(ah, bl[nt], acc[mt][nt], 0, 0, 0);
                acc[mt][nt] = __builtin_amdgcn_mfma_f32_16x16x32_bf16(al, bh[nt], acc[mt][nt], 0, 0, 0);
            }
        }
    }

    // x-pool in-register: D rows (q*4+0, q*4+1) and (q*4+2, q*4+3) are
    // adjacent conv x; pooled x local = mt*8 + q*2 (+1).
#pragma unroll
    for (int mt = 0; mt < 4; ++mt)
#pragma unroll
        for (int nt = 0; nt < 4; ++nt) {
            int oc = nt * 16 + n;
            int plx = mt * 8 + q * 2;
            pool[wsub][plx][oc]     = fmaxf(acc[mt][nt][0], acc[mt][nt][1]);
            pool[wsub][plx + 1][oc] = fmaxf(acc[mt][nt][2], acc[mt][nt][3]);
        }
    __syncthreads();

    // y-pool + bias + relu + split + NHWC write. thread: poolx = tid>>2,
    // oc group = (tid&3)*16.
    {
        int plx = tid >> 2, ocq = tid & 3;
        int wp = plx >> 5, pl = plx & 31;
        __attribute__((aligned(16))) ushort hb[16], lb[16];
#pragma unroll
        for (int e = 0; e < 16; ++e) {
            int oc = ocq * 16 + e;
            float v = fmaxf(pool[wp * 2][pl][oc], pool[wp * 2 + 1][pl][oc]);
            v = fmaxf(v + bias[oc], 0.f);
            ushort h = f2bf(v);
            hb[e] = h;
            lb[e] = f2bf(v - bf2f(h));
        }
        int gx = seg * 64 + plx;
        size_t base = (((size_t)((b * 128 + Y) * 128 + gx)) << 7)
                    + stream_base + ocq * 16;
        uint4* dh = (uint4*)(Ahi + base);
        uint4* dl = (uint4*)(Alo + base);
        dh[0] = *(const uint4*)&hb[0];
        dh[1] = *(const uint4*)&hb[8];
        dl[0] = *(const uint4*)&lb[0];
        dl[1] = *(const uint4*)&lb[8];
    }
}

// ---------- wprep: fuse_w fp32 -> fragment-ordered bf16 hi/lo ---------------
// Wf[t][chunk][oc][kk] = W[oc][ic=chunk*32+kk][ky=t/3][kx=t%3]
__global__ __launch_bounds__(256) void wprep(
    const float* __restrict__ fw, ushort* __restrict__ Whi,
    ushort* __restrict__ Wlo)
{
    int idx = blockIdx.x * 256 + threadIdx.x;
    if (idx >= 147456) return;
    int t = idx >> 14;
    int c = (idx >> 12) & 3;
    int oc = (idx >> 5) & 127;
    int kk = idx & 31;
    int ic = c * 32 + kk;
    int ky = t / 3, kx = t - ky * 3;
    float v = fw[((oc * 128 + ic) * 3 + ky) * 3 + kx];
    ushort h = f2bf(v);
    Whi[idx] = h;
    Wlo[idx] = f2bf(v - bf2f(h));
}

// ---------- Kernel C: fuse conv via split-bf16 MFMA + relu + global mean ----
__global__ __launch_bounds__(256) void fuse_mfma(
    const ushort* __restrict__ Ahi, const ushort* __restrict__ Alo,
    const ushort* __restrict__ Whi, const ushort* __restrict__ Wlo,
    const float* __restrict__ bias, float* __restrict__ featsum)
{
    __shared__ ushort ldsB[2][2][4096];   // [parity][hi/lo][32k x 128oc]
    __shared__ float partial[4][128];
    const int seg = blockIdx.x, y = blockIdx.y, b = blockIdx.z;
    const int tid = threadIdx.x, wsub = tid >> 6, lane = tid & 63;
    const int n = lane & 15, q = lane >> 4;
    const int x0 = seg * 64 + wsub * 16;

    f32x4 acc[8];
#pragma unroll
    for (int g = 0; g < 8; ++g) acc[g] = (f32x4){0.f, 0.f, 0.f, 0.f};

    const uint4 zero4 = make_uint4(0u, 0u, 0u, 0u);
    uint4 pAh = zero4, pAl = zero4;

    auto loadA = [&](int tc, uint4& oh, uint4& ol) {
        int t = tc >> 2, c = tc & 3;
        int ky = t / 3, kx = t - ky * 3;
        int yy = y + ky - 1;
        int xp = x0 + n + kx - 1;
        bool ok = (yy >= 0) & (yy < 128) & (xp >= 0) & (xp < 128);
        int yyc = ok ? yy : 0, xpc = ok ? xp : 0;
        size_t aoff = ((size_t)((b * 128 + yyc) * 128 + xpc) << 7) + c * 32 + q * 8;
        oh = ok ? *(const uint4*)(Ahi + aoff) : zero4;
        ol = ok ? *(const uint4*)(Alo + aoff) : zero4;
    };
    auto stageB = [&](int tc, int par) {
        int gbase = tc * 4096 + tid * 16;
        const uint4* gh = (const uint4*)(Whi + gbase);
        const uint4* gl = (const uint4*)(Wlo + gbase);
        uint4* dh = (uint4*)&ldsB[par][0][tid * 16];
        uint4* dl = (uint4*)&ldsB[par][1][tid * 16];
        dh[0] = gh[0]; dh[1] = gh[1];
        dl[0] = gl[0]; dl[1] = gl[1];
    };

    loadA(0, pAh, pAl);
    stageB(0, 0);

    for (int tc = 0; tc < 36; ++tc) {
        const int par = tc & 1;
        __syncthreads();
        uint4 cAh = pAh, cAl = pAl;
        if (tc + 1 < 36) {
            loadA(tc + 1, pAh, pAl);
            stageB(tc + 1, par ^ 1);
        }
        bf16x8 ah = __builtin_bit_cast(bf16x8, cAh);
        bf16x8 al = __builtin_bit_cast(bf16x8, cAl);
#pragma unroll
        for (int g = 0; g < 8; ++g) {
            const uint4* bh4 = (const uint4*)&ldsB[par][0][(g * 16 + n) * 32 + q * 8];
            const uint4* bl4 = (const uint4*)&ldsB[par][1][(g * 16 + n) * 32 + q * 8];
            bf16x8 bh = __builtin_bit_cast(bf16x8, *bh4);
            bf16x8 bl = __builtin_bit_cast(bf16x8, *bl4);
            acc[g] = __builtin_amdgcn_mfma_f32_16x16x32_bf16(ah, bh, acc[g], 0, 0, 0);
            acc[g] = __builtin_amdgcn_mfma_f32_16x16x32_bf16(ah, bl, acc[g], 0, 0, 0);
            acc[g] = __builtin_amdgcn_mfma_f32_16x16x32_bf16(al, bh, acc[g], 0, 0, 0);
        }
    }

#pragma unroll
    for (int g = 0; g < 8; ++g) {
        float bv = bias[g * 16 + n];
        float v = 0.f;
#pragma unroll
        for (int r = 0; r < 4; ++r) v += fmaxf(acc[g][r] + bv, 0.f);
        v += __shfl_xor(v, 16);
        v += __shfl_xor(v, 32);
        if (lane < 16) partial[wsub][g * 16 + lane] = v;
    }
    __syncthreads();
    if (tid < 128) {
        float v = partial[0][tid] + partial[1][tid] + partial[2][tid] + partial[3][tid];
        atomicAdd(&featsum[b * 128 + tid], v);
    }
}

// ---------- Kernel D: det head + sigmoid + NMS + outputs --------------------
__global__ void det_nms(const float* __restrict__ featsum,
                        const float* __restrict__ dw, const float* __restrict__ db,
                        float* __restrict__ out)
{
    const int b = threadIdx.x;
    if (b >= 8) return;
    const float inv = 1.0f / 16384.0f;

    float p[18];
    for (int j = 0; j < 18; ++j) {
        float a = db[j];
        const float* wp = &dw[j * 128];
        const float* f = &featsum[b * 128];
        for (int c = 0; c < 128; ++c) a = fmaf(wp[c], f[c] * inv, a);
        p[j] = a;
    }
    for (int a = 0; a < 3; ++a)
        for (int e = 0; e < 6; ++e) out[b * 18 + a * 6 + e] = p[a * 6 + e];

    float bx[3][4], sc[3];
    bool ck[3];
    for (int a = 0; a < 3; ++a) {
        for (int k = 0; k < 4; ++k) {
            bx[a][k] = p[a * 6 + k];
            out[144 + b * 12 + a * 4 + k] = bx[a][k];
        }
        float sg = 1.f / (1.f + expf(-p[a * 6 + 4]));
        sc[a] = sg;
        ck[a] = sg > 0.5f;
        out[240 + b * 3 + a] = sg;
    }

    float key[3];
    int order[3];
    bool used[3] = {false, false, false};
    for (int a = 0; a < 3; ++a) key[a] = ck[a] ? sc[a] : -INFINITY;
    for (int i = 0; i < 3; ++i) {
        int best = -1;
        float bk = 0.f;
        for (int a = 0; a < 3; ++a) {
            if (used[a]) continue;
            if (best < 0 || key[a] > bk) { best = a; bk = key[a]; }
        }
        order[i] = best;
        used[best] = true;
    }

    float X1[3], Y1[3], X2[3], Y2[3], AR[3];
    for (int i = 0; i < 3; ++i) {
        int o = order[i];
        X1[i] = bx[o][0]; Y1[i] = bx[o][1];
        X2[i] = bx[o][2]; Y2[i] = bx[o][3];
        AR[i] = (X2[i] - X1[i]) * (Y2[i] - Y1[i]);
    }
    bool suppressed[3] = {false, false, false}, keep_s[3];
    for (int i = 0; i < 3; ++i) {
        bool valid = !suppressed[i];
        keep_s[i] = valid;
        if (valid) {
            for (int j = i + 1; j < 3; ++j) {
                float ix1 = fmaxf(X1[i], X1[j]), iy1 = fmaxf(Y1[i], Y1[j]);
                float ix2 = fminf(X2[i], X2[j]), iy2 = fminf(Y2[i], Y2[j]);
                float inter = fmaxf(ix2 - ix1, 0.f) * fmaxf(iy2 - iy1, 0.f);
                float iou = inter / (AR[i] + AR[j] - inter);
                if (iou > 0.5f) suppressed[j] = true;
            }
        }
    }
    bool keep[3];
    for (int i = 0; i < 3; ++i) keep[order[i]] = keep_s[i];
    for (int a = 0; a < 3; ++a)
        out[264 + b * 3 + a] = (keep[a] && ck[a]) ? 1.f : 0.f;
}

__global__ void zero_feat(float* __restrict__ p)
{
    int i = blockIdx.x * 256 + threadIdx.x;
    if (i < 1024) p[i] = 0.f;
}

// ---------------------------------------------------------------------------
extern "C" void kernel_launch(void* const* d_in, const int* in_sizes, int n_in,
                              void* d_out, int out_size, void* d_ws, size_t ws_size,
                              hipStream_t stream)
{
    const float* x      = (const float*)d_in[0];
    const float* rgb_w1 = (const float*)d_in[1];
    const float* rgb_b1 = (const float*)d_in[2];
    const float* rgb_w2 = (const float*)d_in[3];
    const float* rgb_b2 = (const float*)d_in[4];
    const float* ir_w1  = (const float*)d_in[5];
    const float* ir_b1  = (const float*)d_in[6];
    const float* ir_w2  = (const float*)d_in[7];
    const float* ir_b2  = (const float*)d_in[8];
    const float* fuse_w = (const float*)d_in[9];
    const float* fuse_b = (const float*)d_in[10];
    const float* det_w  = (const float*)d_in[11];
    const float* det_b  = (const float*)d_in[12];
    float* out = (float*)d_out;

    char* ws = (char*)d_ws;
    // [0, 67MB): C1 hi/lo (one stream at a time); overwritten by W/feat after
    // conv2(ir). [67MB, 134MB): fuse input A hi/lo (both streams' channels).
    ushort* C1h  = (ushort*)(ws);                         // 33,554,432 B
    ushort* C1l  = (ushort*)(ws + 33554432);              // 33,554,432 B
    ushort* Whi  = (ushort*)(ws);                         // 294,912 B (post-conv2)
    ushort* Wlo  = (ushort*)(ws + 294912);                // 294,912 B
    float*  feat = (float*)(ws + 589824);                 // 4,096 B
    ushort* Ahi  = (ushort*)(ws + 67108864);              // 33,554,432 B
    ushort* Alo  = (ushort*)(ws + 100663296);             // 33,554,432 B

    dim3 blk(256);
    hipLaunchKernelGGL(conv1_pool, dim3(16, 16, 8), blk, 0, stream, x, rgb_w1, rgb_b1, C1h, C1l);
    hipLaunchKernelGGL(conv2_mfma, dim3(2, 128, 8), blk, 0, stream, C1h, C1l, rgb_w2, rgb_b2, Ahi, Alo, 0);
    hipLaunchKernelGGL(conv1_pool, dim3(16, 16, 8), blk, 0, stream, x, ir_w1, ir_b1, C1h, C1l);
    hipLaunchKernelGGL(conv2_mfma, dim3(2, 128, 8), blk, 0, stream, C1h, C1l, ir_w2, ir_b2, Ahi, Alo, 64);
    // C1 now dead: safe to overwrite its region with W/feat
    hipLaunchKernelGGL(wprep, dim3(576), blk, 0, stream, fuse_w, Whi, Wlo);
    hipLaunchKernelGGL(zero_feat, dim3(4), blk, 0, stream, feat);
    hipLaunchKernelGGL(fuse_mfma, dim3(2, 128, 8), blk, 0, stream, Ahi, Alo, Whi, Wlo, fuse_b, feat);
    hipLaunchKernelGGL(det_nms, dim3(1), dim3(64), 0, stream, feat, det_w, det_b, out);
}

// Round 6
// 726.012 us; speedup vs baseline: 1.5133x; 1.0459x over previous
//
#include <hip/hip_runtime.h>
#include <math.h>

// ---------------------------------------------------------------------------
// MultiStreamCNN. R6: fuse_mfma restructured — each wave now owns 4 M-tiles
// (64 px) x 128 oc, so each B-fragment LDS read feeds 12 MFMAs instead of 3.
// R5 analysis: fuse was LDS-BW-bound on B reads (each wave re-read the whole
// 16KB B tile per tap-chunk; wave64 b128 = 8 mandatory bank phases). conv1 /
// conv2 / wprep / det unchanged from R5 (absmax 0.0).
// ---------------------------------------------------------------------------

typedef __bf16 bf16x8 __attribute__((ext_vector_type(8)));
typedef float f32x4 __attribute__((ext_vector_type(4)));

static __device__ __forceinline__ ushort f2bf(float f) {
    unsigned u = __float_as_uint(f);
    unsigned r = (u + 0x7fffu + ((u >> 16) & 1u)) >> 16;   // RNE
    return (ushort)r;
}
static __device__ __forceinline__ float bf2f(ushort h) {
    return __uint_as_float(((unsigned)h) << 16);
}

// ---------- Kernel A: conv3x3 (3->32) + bias + relu + maxpool2 --------------
// in x: (8,3,512,512); out: NHWC bf16 hi/lo ((b*256+y)*256+x)*32 + oc.
__global__ __launch_bounds__(256) void conv1_pool(
    const float* __restrict__ x, const float* __restrict__ w,
    const float* __restrict__ bias, ushort* __restrict__ C1h,
    ushort* __restrict__ C1l)
{
    __shared__ float s[3 * 34 * 34];
    const int b = blockIdx.z;
    const int tileX = blockIdx.x, tileY = blockIdx.y;
    const int tid = threadIdx.x;
    const int tx = tid & 15, ty = tid >> 4;
    const int ih0 = tileY * 32 - 1, iw0 = tileX * 32 - 1;

    for (int i = tid; i < 3 * 34 * 34; i += 256) {
        int c = i / 1156, r = i % 1156;
        int y = r / 34, xx = r % 34;
        int ih = ih0 + y, iw = iw0 + xx;
        float v = 0.f;
        if (ih >= 0 && ih < 512 && iw >= 0 && iw < 512)
            v = x[((b * 3 + c) * 512 + ih) * 512 + iw];
        s[i] = v;
    }
    __syncthreads();

    float in[3][4][4];
#pragma unroll
    for (int c = 0; c < 3; ++c)
#pragma unroll
        for (int dy = 0; dy < 4; ++dy)
#pragma unroll
            for (int dx = 0; dx < 4; ++dx)
                in[c][dy][dx] = s[c * 1156 + (2 * ty + dy) * 34 + (2 * tx + dx)];

    const int oh = tileY * 16 + ty, ow = tileX * 16 + tx;
    __attribute__((aligned(16))) ushort hb[32];
    __attribute__((aligned(16))) ushort lb[32];
    for (int oc = 0; oc < 32; ++oc) {
        const float bv = bias[oc];
        float m = -INFINITY;
#pragma unroll
        for (int py = 0; py < 2; ++py)
#pragma unroll
            for (int px = 0; px < 2; ++px) {
                float a = 0.f;
#pragma unroll
                for (int c = 0; c < 3; ++c)
#pragma unroll
                    for (int ky = 0; ky < 3; ++ky)
#pragma unroll
                        for (int kx = 0; kx < 3; ++kx)
                            a = fmaf(w[((oc * 3 + c) * 3 + ky) * 3 + kx],
                                     in[c][py + ky][px + kx], a);
                m = fmaxf(m, a);
            }
        m = fmaxf(m + bv, 0.f);
        ushort h = f2bf(m);
        hb[oc] = h;
        lb[oc] = f2bf(m - bf2f(h));
    }
    size_t base = ((size_t)((b * 256 + oh) * 256 + ow)) << 5;
    uint4* dh = (uint4*)(C1h + base);
    uint4* dl = (uint4*)(C1l + base);
#pragma unroll
    for (int k = 0; k < 4; ++k) {
        dh[k] = *(const uint4*)&hb[k * 8];
        dl[k] = *(const uint4*)&lb[k * 8];
    }
}

// ---------- Kernel B: conv2 as split-bf16 MFMA + maxpool2 -------------------
__global__ __launch_bounds__(256) void conv2_mfma(
    const ushort* __restrict__ C1h, const ushort* __restrict__ C1l,
    const float* __restrict__ w2, const float* __restrict__ bias,
    ushort* __restrict__ Ahi, ushort* __restrict__ Alo, int stream_base)
{
    __shared__ ushort Bh[2][2048];   // [parity][oc*32+ic]
    __shared__ ushort Bl[2][2048];
    __shared__ float pool[4][32][64];  // [wsub][poolx_local][oc]
    const int seg = blockIdx.x, Y = blockIdx.y, b = blockIdx.z;
    const int tid = threadIdx.x, wsub = tid >> 6, lane = tid & 63;
    const int n = lane & 15, q = lane >> 4;
    const int yc = 2 * Y + (wsub & 1);              // conv row in [0,256)
    const int wx0 = seg * 128 + (wsub >> 1) * 64;   // conv x base for wave

    const uint4 zero4 = make_uint4(0u, 0u, 0u, 0u);
    const int woc = tid >> 2, wicb = (tid & 3) * 8;

    auto loadW = [&](int t, float* wr) {
#pragma unroll
        for (int e = 0; e < 8; ++e)
            wr[e] = w2[(woc * 32 + wicb + e) * 9 + t];
    };
    auto loadA = [&](int t, uint4* aH, uint4* aL) {
        int ky = t / 3, kx = t - ky * 3;
        int yy = yc + ky - 1;
        bool yok = (yy >= 0) & (yy < 256);
#pragma unroll
        for (int mt = 0; mt < 4; ++mt) {
            int xp = wx0 + mt * 16 + n + kx - 1;
            bool ok = yok & (xp >= 0) & (xp < 256);
            int yyc = ok ? yy : 0, xpc = ok ? xp : 0;
            size_t off = (((size_t)((b * 256 + yyc) * 256 + xpc)) << 5) + q * 8;
            aH[mt] = ok ? *(const uint4*)(C1h + off) : zero4;
            aL[mt] = ok ? *(const uint4*)(C1l + off) : zero4;
        }
    };

    f32x4 acc[4][4];
#pragma unroll
    for (int mt = 0; mt < 4; ++mt)
#pragma unroll
        for (int nt = 0; nt < 4; ++nt) acc[mt][nt] = (f32x4){0.f, 0.f, 0.f, 0.f};

    float wr[8];
    uint4 aH[4], aL[4];
    loadW(0, wr);
    loadA(0, aH, aL);

    for (int t = 0; t < 9; ++t) {
        const int par = t & 1;
        __attribute__((aligned(16))) ushort hb8[8], lb8[8];
#pragma unroll
        for (int e = 0; e < 8; ++e) {
            ushort h = f2bf(wr[e]);
            hb8[e] = h;
            lb8[e] = f2bf(wr[e] - bf2f(h));
        }
        *(uint4*)&Bh[par][tid * 8] = *(const uint4*)&hb8[0];
        *(uint4*)&Bl[par][tid * 8] = *(const uint4*)&lb8[0];
        __syncthreads();
        uint4 cH[4], cL[4];
#pragma unroll
        for (int mt = 0; mt < 4; ++mt) { cH[mt] = aH[mt]; cL[mt] = aL[mt]; }
        if (t + 1 < 9) {
            loadW(t + 1, wr);
            loadA(t + 1, aH, aL);
        }
        bf16x8 bh[4], bl[4];
#pragma unroll
        for (int nt = 0; nt < 4; ++nt) {
            int oc = nt * 16 + n;
            bh[nt] = __builtin_bit_cast(bf16x8, *(const uint4*)&Bh[par][oc * 32 + q * 8]);
            bl[nt] = __builtin_bit_cast(bf16x8, *(const uint4*)&Bl[par][oc * 32 + q * 8]);
        }
#pragma unroll
        for (int mt = 0; mt < 4; ++mt) {
            bf16x8 ah = __builtin_bit_cast(bf16x8, cH[mt]);
            bf16x8 al = __builtin_bit_cast(bf16x8, cL[mt]);
#pragma unroll
            for (int nt = 0; nt < 4; ++nt) {
                acc[mt][nt] = __builtin_amdgcn_mfma_f32_16x16x32_bf16(ah, bh[nt], acc[mt][nt], 0, 0, 0);
                acc[mt][nt] = __builtin_amdgcn_mfma_f32_16x16x32_bf16(ah, bl[nt], acc[mt][nt], 0, 0, 0);
                acc[mt][nt] = __builtin_amdgcn_mfma_f32_16x16x32_bf16(al, bh[nt], acc[mt][nt], 0, 0, 0);
            }
        }
    }

#pragma unroll
    for (int mt = 0; mt < 4; ++mt)
#pragma unroll
        for (int nt = 0; nt < 4; ++nt) {
            int oc = nt * 16 + n;
            int plx = mt * 8 + q * 2;
            pool[wsub][plx][oc]     = fmaxf(acc[mt][nt][0], acc[mt][nt][1]);
            pool[wsub][plx + 1][oc] = fmaxf(acc[mt][nt][2], acc[mt][nt][3]);
        }
    __syncthreads();

    {
        int plx = tid >> 2, ocq = tid & 3;
        int wp = plx >> 5, pl = plx & 31;
        __attribute__((aligned(16))) ushort hb[16], lb[16];
#pragma unroll
        for (int e = 0; e < 16; ++e) {
            int oc = ocq * 16 + e;
            float v = fmaxf(pool[wp * 2][pl][oc], pool[wp * 2 + 1][pl][oc]);
            v = fmaxf(v + bias[oc], 0.f);
            ushort h = f2bf(v);
            hb[e] = h;
            lb[e] = f2bf(v - bf2f(h));
        }
        int gx = seg * 64 + plx;
        size_t base = (((size_t)((b * 128 + Y) * 128 + gx)) << 7)
                    + stream_base + ocq * 16;
        uint4* dh = (uint4*)(Ahi + base);
        uint4* dl = (uint4*)(Alo + base);
        dh[0] = *(const uint4*)&hb[0];
        dh[1] = *(const uint4*)&hb[8];
        dl[0] = *(const uint4*)&lb[0];
        dl[1] = *(const uint4*)&lb[8];
    }
}

// ---------- wprep: fuse_w fp32 -> fragment-ordered bf16 hi/lo ---------------
__global__ __launch_bounds__(256) void wprep(
    const float* __restrict__ fw, ushort* __restrict__ Whi,
    ushort* __restrict__ Wlo)
{
    int idx = blockIdx.x * 256 + threadIdx.x;
    if (idx >= 147456) return;
    int t = idx >> 14;
    int c = (idx >> 12) & 3;
    int oc = (idx >> 5) & 127;
    int kk = idx & 31;
    int ic = c * 32 + kk;
    int ky = t / 3, kx = t - ky * 3;
    float v = fw[((oc * 128 + ic) * 3 + ky) * 3 + kx];
    ushort h = f2bf(v);
    Whi[idx] = h;
    Wlo[idx] = f2bf(v - bf2f(h));
}

// ---------- Kernel C: fuse conv via split-bf16 MFMA + relu + global mean ----
// Block: 256 px (2 rows of 128) x 128 oc. Wave = 64 px (4 M-tiles) x 128 oc:
// each B-frag LDS read feeds 12 MFMAs (was 3 in R5 — LDS-BW-bound).
// grid: (ypair 0..63, b 0..7).
__global__ __launch_bounds__(256, 2) void fuse_mfma(
    const ushort* __restrict__ Ahi, const ushort* __restrict__ Alo,
    const ushort* __restrict__ Whi, const ushort* __restrict__ Wlo,
    const float* __restrict__ bias, float* __restrict__ featsum)
{
    __shared__ ushort ldsB[2][2][4096];   // [parity][hi/lo][32k x 128oc]
    __shared__ float partial[4][128];
    const int ypair = blockIdx.x, b = blockIdx.y;
    const int tid = threadIdx.x, wsub = tid >> 6, lane = tid & 63;
    const int n = lane & 15, q = lane >> 4;
    const int y = ypair * 2 + (wsub >> 1);       // conv row for this wave
    const int xbase = (wsub & 1) * 64;           // wave covers x [xbase,xbase+64)

    f32x4 acc[4][8];
#pragma unroll
    for (int mt = 0; mt < 4; ++mt)
#pragma unroll
        for (int g = 0; g < 8; ++g) acc[mt][g] = (f32x4){0.f, 0.f, 0.f, 0.f};

    const uint4 zero4 = make_uint4(0u, 0u, 0u, 0u);

    auto loadA = [&](int tc, uint4* oh, uint4* ol) {
        int t = tc >> 2, c = tc & 3;
        int ky = t / 3, kx = t - ky * 3;
        int yy = y + ky - 1;
        bool yok = (yy >= 0) & (yy < 128);
#pragma unroll
        for (int mt = 0; mt < 4; ++mt) {
            int xp = xbase + mt * 16 + n + kx - 1;
            bool ok = yok & (xp >= 0) & (xp < 128);
            int yyc = ok ? yy : 0, xpc = ok ? xp : 0;
            size_t aoff = ((size_t)((b * 128 + yyc) * 128 + xpc) << 7) + c * 32 + q * 8;
            oh[mt] = ok ? *(const uint4*)(Ahi + aoff) : zero4;
            ol[mt] = ok ? *(const uint4*)(Alo + aoff) : zero4;
        }
    };
    auto stageB = [&](int tc, int par) {
        int gbase = tc * 4096 + tid * 16;
        const uint4* gh = (const uint4*)(Whi + gbase);
        const uint4* gl = (const uint4*)(Wlo + gbase);
        uint4* dh = (uint4*)&ldsB[par][0][tid * 16];
        uint4* dl = (uint4*)&ldsB[par][1][tid * 16];
        dh[0] = gh[0]; dh[1] = gh[1];
        dl[0] = gl[0]; dl[1] = gl[1];
    };

    uint4 pAh[4], pAl[4];
    loadA(0, pAh, pAl);
    stageB(0, 0);

    for (int tc = 0; tc < 36; ++tc) {
        const int par = tc & 1;
        __syncthreads();
        uint4 cAh[4], cAl[4];
#pragma unroll
        for (int mt = 0; mt < 4; ++mt) { cAh[mt] = pAh[mt]; cAl[mt] = pAl[mt]; }
        if (tc + 1 < 36) {
            loadA(tc + 1, pAh, pAl);
            stageB(tc + 1, par ^ 1);
        }
#pragma unroll
        for (int g = 0; g < 8; ++g) {
            const uint4* bh4 = (const uint4*)&ldsB[par][0][(g * 16 + n) * 32 + q * 8];
            const uint4* bl4 = (const uint4*)&ldsB[par][1][(g * 16 + n) * 32 + q * 8];
            bf16x8 bh = __builtin_bit_cast(bf16x8, *bh4);
            bf16x8 bl = __builtin_bit_cast(bf16x8, *bl4);
#pragma unroll
            for (int mt = 0; mt < 4; ++mt) {
                bf16x8 ah = __builtin_bit_cast(bf16x8, cAh[mt]);
                bf16x8 al = __builtin_bit_cast(bf16x8, cAl[mt]);
                acc[mt][g] = __builtin_amdgcn_mfma_f32_16x16x32_bf16(ah, bh, acc[mt][g], 0, 0, 0);
                acc[mt][g] = __builtin_amdgcn_mfma_f32_16x16x32_bf16(ah, bl, acc[mt][g], 0, 0, 0);
                acc[mt][g] = __builtin_amdgcn_mfma_f32_16x16x32_bf16(al, bh, acc[mt][g], 0, 0, 0);
            }
        }
    }

    // Epilogue: lane (q,n) of tile (mt,g) holds D[px = q*4+r][oc = g*16+n].
#pragma unroll
    for (int g = 0; g < 8; ++g) {
        float bv = bias[g * 16 + n];
        float v = 0.f;
#pragma unroll
        for (int mt = 0; mt < 4; ++mt)
#pragma unroll
            for (int r = 0; r < 4; ++r) v += fmaxf(acc[mt][g][r] + bv, 0.f);
        v += __shfl_xor(v, 16);
        v += __shfl_xor(v, 32);
        if (lane < 16) partial[wsub][g * 16 + lane] = v;
    }
    __syncthreads();
    if (tid < 128) {
        float v = partial[0][tid] + partial[1][tid] + partial[2][tid] + partial[3][tid];
        atomicAdd(&featsum[b * 128 + tid], v);
    }
}

// ---------- Kernel D: det head + sigmoid + NMS + outputs --------------------
__global__ void det_nms(const float* __restrict__ featsum,
                        const float* __restrict__ dw, const float* __restrict__ db,
                        float* __restrict__ out)
{
    const int b = threadIdx.x;
    if (b >= 8) return;
    const float inv = 1.0f / 16384.0f;

    float p[18];
    for (int j = 0; j < 18; ++j) {
        float a = db[j];
        const float* wp = &dw[j * 128];
        const float* f = &featsum[b * 128];
        for (int c = 0; c < 128; ++c) a = fmaf(wp[c], f[c] * inv, a);
        p[j] = a;
    }
    for (int a = 0; a < 3; ++a)
        for (int e = 0; e < 6; ++e) out[b * 18 + a * 6 + e] = p[a * 6 + e];

    float bx[3][4], sc[3];
    bool ck[3];
    for (int a = 0; a < 3; ++a) {
        for (int k = 0; k < 4; ++k) {
            bx[a][k] = p[a * 6 + k];
            out[144 + b * 12 + a * 4 + k] = bx[a][k];
        }
        float sg = 1.f / (1.f + expf(-p[a * 6 + 4]));
        sc[a] = sg;
        ck[a] = sg > 0.5f;
        out[240 + b * 3 + a] = sg;
    }

    float key[3];
    int order[3];
    bool used[3] = {false, false, false};
    for (int a = 0; a < 3; ++a) key[a] = ck[a] ? sc[a] : -INFINITY;
    for (int i = 0; i < 3; ++i) {
        int best = -1;
        float bk = 0.f;
        for (int a = 0; a < 3; ++a) {
            if (used[a]) continue;
            if (best < 0 || key[a] > bk) { best = a; bk = key[a]; }
        }
        order[i] = best;
        used[best] = true;
    }

    float X1[3], Y1[3], X2[3], Y2[3], AR[3];
    for (int i = 0; i < 3; ++i) {
        int o = order[i];
        X1[i] = bx[o][0]; Y1[i] = bx[o][1];
        X2[i] = bx[o][2]; Y2[i] = bx[o][3];
        AR[i] = (X2[i] - X1[i]) * (Y2[i] - Y1[i]);
    }
    bool suppressed[3] = {false, false, false}, keep_s[3];
    for (int i = 0; i < 3; ++i) {
        bool valid = !suppressed[i];
        keep_s[i] = valid;
        if (valid) {
            for (int j = i + 1; j < 3; ++j) {
                float ix1 = fmaxf(X1[i], X1[j]), iy1 = fmaxf(Y1[i], Y1[j]);
                float ix2 = fminf(X2[i], X2[j]), iy2 = fminf(Y2[i], Y2[j]);
                float inter = fmaxf(ix2 - ix1, 0.f) * fmaxf(iy2 - iy1, 0.f);
                float iou = inter / (AR[i] + AR[j] - inter);
                if (iou > 0.5f) suppressed[j] = true;
            }
        }
    }
    bool keep[3];
    for (int i = 0; i < 3; ++i) keep[order[i]] = keep_s[i];
    for (int a = 0; a < 3; ++a)
        out[264 + b * 3 + a] = (keep[a] && ck[a]) ? 1.f : 0.f;
}

__global__ void zero_feat(float* __restrict__ p)
{
    int i = blockIdx.x * 256 + threadIdx.x;
    if (i < 1024) p[i] = 0.f;
}

// ---------------------------------------------------------------------------
extern "C" void kernel_launch(void* const* d_in, const int* in_sizes, int n_in,
                              void* d_out, int out_size, void* d_ws, size_t ws_size,
                              hipStream_t stream)
{
    const float* x      = (const float*)d_in[0];
    const float* rgb_w1 = (const float*)d_in[1];
    const float* rgb_b1 = (const float*)d_in[2];
    const float* rgb_w2 = (const float*)d_in[3];
    const float* rgb_b2 = (const float*)d_in[4];
    const float* ir_w1  = (const float*)d_in[5];
    const float* ir_b1  = (const float*)d_in[6];
    const float* ir_w2  = (const float*)d_in[7];
    const float* ir_b2  = (const float*)d_in[8];
    const float* fuse_w = (const float*)d_in[9];
    const float* fuse_b = (const float*)d_in[10];
    const float* det_w  = (const float*)d_in[11];
    const float* det_b  = (const float*)d_in[12];
    float* out = (float*)d_out;

    char* ws = (char*)d_ws;
    ushort* C1h  = (ushort*)(ws);                         // 33,554,432 B
    ushort* C1l  = (ushort*)(ws + 33554432);              // 33,554,432 B
    ushort* Whi  = (ushort*)(ws);                         // 294,912 B (post-conv2)
    ushort* Wlo  = (ushort*)(ws + 294912);                // 294,912 B
    float*  feat = (float*)(ws + 589824);                 // 4,096 B
    ushort* Ahi  = (ushort*)(ws + 67108864);              // 33,554,432 B
    ushort* Alo  = (ushort*)(ws + 100663296);             // 33,554,432 B

    dim3 blk(256);
    hipLaunchKernelGGL(conv1_pool, dim3(16, 16, 8), blk, 0, stream, x, rgb_w1, rgb_b1, C1h, C1l);
    hipLaunchKernelGGL(conv2_mfma, dim3(2, 128, 8), blk, 0, stream, C1h, C1l, rgb_w2, rgb_b2, Ahi, Alo, 0);
    hipLaunchKernelGGL(conv1_pool, dim3(16, 16, 8), blk, 0, stream, x, ir_w1, ir_b1, C1h, C1l);
    hipLaunchKernelGGL(conv2_mfma, dim3(2, 128, 8), blk, 0, stream, C1h, C1l, ir_w2, ir_b2, Ahi, Alo, 64);
    hipLaunchKernelGGL(wprep, dim3(576), blk, 0, stream, fuse_w, Whi, Wlo);
    hipLaunchKernelGGL(zero_feat, dim3(4), blk, 0, stream, feat);
    hipLaunchKernelGGL(fuse_mfma, dim3(64, 8), blk, 0, stream, Ahi, Alo, Whi, Wlo, fuse_b, feat);
    hipLaunchKernelGGL(det_nms, dim3(1), dim3(64), 0, stream, feat, det_w, det_b, out);
}

// Round 7
// 668.097 us; speedup vs baseline: 1.6444x; 1.0867x over previous
//
#include <hip/hip_runtime.h>
#include <math.h>

// ---------------------------------------------------------------------------
// MultiStreamCNN. R7:
//  - conv1: #pragma unroll on the oc epilogue loop (R6 profile showed hb[oc]
//    dynamic indexing -> scratch spills: FETCH 62MB/WRITE 131MB vs 8/67 ideal).
//  - fuse: B (1.2 MB, L2-resident) loaded per-wave straight from global; NO
//    LDS staging, NO barriers in the K-loop -> A-prefetch loads stay in
//    flight (R6: per-tc __syncthreads drained vmcnt(0) every iteration).
//  conv2 / wprep / det unchanged (absmax 0.0 so far).
// ---------------------------------------------------------------------------

typedef __bf16 bf16x8 __attribute__((ext_vector_type(8)));
typedef float f32x4 __attribute__((ext_vector_type(4)));

static __device__ __forceinline__ ushort f2bf(float f) {
    unsigned u = __float_as_uint(f);
    unsigned r = (u + 0x7fffu + ((u >> 16) & 1u)) >> 16;   // RNE
    return (ushort)r;
}
static __device__ __forceinline__ float bf2f(ushort h) {
    return __uint_as_float(((unsigned)h) << 16);
}

// ---------- Kernel A: conv3x3 (3->32) + bias + relu + maxpool2 --------------
// in x: (8,3,512,512); out: NHWC bf16 hi/lo ((b*256+y)*256+x)*32 + oc.
__global__ __launch_bounds__(256) void conv1_pool(
    const float* __restrict__ x, const float* __restrict__ w,
    const float* __restrict__ bias, ushort* __restrict__ C1h,
    ushort* __restrict__ C1l)
{
    __shared__ float s[3 * 34 * 34];
    const int b = blockIdx.z;
    const int tileX = blockIdx.x, tileY = blockIdx.y;
    const int tid = threadIdx.x;
    const int tx = tid & 15, ty = tid >> 4;
    const int ih0 = tileY * 32 - 1, iw0 = tileX * 32 - 1;

    for (int i = tid; i < 3 * 34 * 34; i += 256) {
        int c = i / 1156, r = i % 1156;
        int y = r / 34, xx = r % 34;
        int ih = ih0 + y, iw = iw0 + xx;
        float v = 0.f;
        if (ih >= 0 && ih < 512 && iw >= 0 && iw < 512)
            v = x[((b * 3 + c) * 512 + ih) * 512 + iw];
        s[i] = v;
    }
    __syncthreads();

    float in[3][4][4];
#pragma unroll
    for (int c = 0; c < 3; ++c)
#pragma unroll
        for (int dy = 0; dy < 4; ++dy)
#pragma unroll
            for (int dx = 0; dx < 4; ++dx)
                in[c][dy][dx] = s[c * 1156 + (2 * ty + dy) * 34 + (2 * tx + dx)];

    const int oh = tileY * 16 + ty, ow = tileX * 16 + tx;
    __attribute__((aligned(16))) ushort hb[32];
    __attribute__((aligned(16))) ushort lb[32];
#pragma unroll
    for (int oc = 0; oc < 32; ++oc) {   // FULL unroll: hb/lb must stay in VGPRs
        const float bv = bias[oc];
        float m = -INFINITY;
#pragma unroll
        for (int py = 0; py < 2; ++py)
#pragma unroll
            for (int px = 0; px < 2; ++px) {
                float a = 0.f;
#pragma unroll
                for (int c = 0; c < 3; ++c)
#pragma unroll
                    for (int ky = 0; ky < 3; ++ky)
#pragma unroll
                        for (int kx = 0; kx < 3; ++kx)
                            a = fmaf(w[((oc * 3 + c) * 3 + ky) * 3 + kx],
                                     in[c][py + ky][px + kx], a);
                m = fmaxf(m, a);
            }
        m = fmaxf(m + bv, 0.f);
        ushort h = f2bf(m);
        hb[oc] = h;
        lb[oc] = f2bf(m - bf2f(h));
    }
    size_t base = ((size_t)((b * 256 + oh) * 256 + ow)) << 5;
    uint4* dh = (uint4*)(C1h + base);
    uint4* dl = (uint4*)(C1l + base);
#pragma unroll
    for (int k = 0; k < 4; ++k) {
        dh[k] = *(const uint4*)&hb[k * 8];
        dl[k] = *(const uint4*)&lb[k * 8];
    }
}

// ---------- Kernel B: conv2 as split-bf16 MFMA + maxpool2 -------------------
__global__ __launch_bounds__(256) void conv2_mfma(
    const ushort* __restrict__ C1h, const ushort* __restrict__ C1l,
    const float* __restrict__ w2, const float* __restrict__ bias,
    ushort* __restrict__ Ahi, ushort* __restrict__ Alo, int stream_base)
{
    __shared__ ushort Bh[2][2048];   // [parity][oc*32+ic]
    __shared__ ushort Bl[2][2048];
    __shared__ float pool[4][32][64];  // [wsub][poolx_local][oc]
    const int seg = blockIdx.x, Y = blockIdx.y, b = blockIdx.z;
    const int tid = threadIdx.x, wsub = tid >> 6, lane = tid & 63;
    const int n = lane & 15, q = lane >> 4;
    const int yc = 2 * Y + (wsub & 1);              // conv row in [0,256)
    const int wx0 = seg * 128 + (wsub >> 1) * 64;   // conv x base for wave

    const uint4 zero4 = make_uint4(0u, 0u, 0u, 0u);
    const int woc = tid >> 2, wicb = (tid & 3) * 8;

    auto loadW = [&](int t, float* wr) {
#pragma unroll
        for (int e = 0; e < 8; ++e)
            wr[e] = w2[(woc * 32 + wicb + e) * 9 + t];
    };
    auto loadA = [&](int t, uint4* aH, uint4* aL) {
        int ky = t / 3, kx = t - ky * 3;
        int yy = yc + ky - 1;
        bool yok = (yy >= 0) & (yy < 256);
#pragma unroll
        for (int mt = 0; mt < 4; ++mt) {
            int xp = wx0 + mt * 16 + n + kx - 1;
            bool ok = yok & (xp >= 0) & (xp < 256);
            int yyc = ok ? yy : 0, xpc = ok ? xp : 0;
            size_t off = (((size_t)((b * 256 + yyc) * 256 + xpc)) << 5) + q * 8;
            aH[mt] = ok ? *(const uint4*)(C1h + off) : zero4;
            aL[mt] = ok ? *(const uint4*)(C1l + off) : zero4;
        }
    };

    f32x4 acc[4][4];
#pragma unroll
    for (int mt = 0; mt < 4; ++mt)
#pragma unroll
        for (int nt = 0; nt < 4; ++nt) acc[mt][nt] = (f32x4){0.f, 0.f, 0.f, 0.f};

    float wr[8];
    uint4 aH[4], aL[4];
    loadW(0, wr);
    loadA(0, aH, aL);

    for (int t = 0; t < 9; ++t) {
        const int par = t & 1;
        __attribute__((aligned(16))) ushort hb8[8], lb8[8];
#pragma unroll
        for (int e = 0; e < 8; ++e) {
            ushort h = f2bf(wr[e]);
            hb8[e] = h;
            lb8[e] = f2bf(wr[e] - bf2f(h));
        }
        *(uint4*)&Bh[par][tid * 8] = *(const uint4*)&hb8[0];
        *(uint4*)&Bl[par][tid * 8] = *(const uint4*)&lb8[0];
        __syncthreads();
        uint4 cH[4], cL[4];
#pragma unroll
        for (int mt = 0; mt < 4; ++mt) { cH[mt] = aH[mt]; cL[mt] = aL[mt]; }
        if (t + 1 < 9) {
            loadW(t + 1, wr);
            loadA(t + 1, aH, aL);
        }
        bf16x8 bh[4], bl[4];
#pragma unroll
        for (int nt = 0; nt < 4; ++nt) {
            int oc = nt * 16 + n;
            bh[nt] = __builtin_bit_cast(bf16x8, *(const uint4*)&Bh[par][oc * 32 + q * 8]);
            bl[nt] = __builtin_bit_cast(bf16x8, *(const uint4*)&Bl[par][oc * 32 + q * 8]);
        }
#pragma unroll
        for (int mt = 0; mt < 4; ++mt) {
            bf16x8 ah = __builtin_bit_cast(bf16x8, cH[mt]);
            bf16x8 al = __builtin_bit_cast(bf16x8, cL[mt]);
#pragma unroll
            for (int nt = 0; nt < 4; ++nt) {
                acc[mt][nt] = __builtin_amdgcn_mfma_f32_16x16x32_bf16(ah, bh[nt], acc[mt][nt], 0, 0, 0);
                acc[mt][nt] = __builtin_amdgcn_mfma_f32_16x16x32_bf16(ah, bl[nt], acc[mt][nt], 0, 0, 0);
                acc[mt][nt] = __builtin_amdgcn_mfma_f32_16x16x32_bf16(al, bh[nt], acc[mt][nt], 0, 0, 0);
            }
        }
    }

#pragma unroll
    for (int mt = 0; mt < 4; ++mt)
#pragma unroll
        for (int nt = 0; nt < 4; ++nt) {
            int oc = nt * 16 + n;
            int plx = mt * 8 + q * 2;
            pool[wsub][plx][oc]     = fmaxf(acc[mt][nt][0], acc[mt][nt][1]);
            pool[wsub][plx + 1][oc] = fmaxf(acc[mt][nt][2], acc[mt][nt][3]);
        }
    __syncthreads();

    {
        int plx = tid >> 2, ocq = tid & 3;
        int wp = plx >> 5, pl = plx & 31;
        __attribute__((aligned(16))) ushort hb[16], lb[16];
#pragma unroll
        for (int e = 0; e < 16; ++e) {
            int oc = ocq * 16 + e;
            float v = fmaxf(pool[wp * 2][pl][oc], pool[wp * 2 + 1][pl][oc]);
            v = fmaxf(v + bias[oc], 0.f);
            ushort h = f2bf(v);
            hb[e] = h;
            lb[e] = f2bf(v - bf2f(h));
        }
        int gx = seg * 64 + plx;
        size_t base = (((size_t)((b * 128 + Y) * 128 + gx)) << 7)
                    + stream_base + ocq * 16;
        uint4* dh = (uint4*)(Ahi + base);
        uint4* dl = (uint4*)(Alo + base);
        dh[0] = *(const uint4*)&hb[0];
        dh[1] = *(const uint4*)&hb[8];
        dl[0] = *(const uint4*)&lb[0];
        dl[1] = *(const uint4*)&lb[8];
    }
}

// ---------- wprep: fuse_w fp32 -> fragment-ordered bf16 hi/lo ---------------
__global__ __launch_bounds__(256) void wprep(
    const float* __restrict__ fw, ushort* __restrict__ Whi,
    ushort* __restrict__ Wlo)
{
    int idx = blockIdx.x * 256 + threadIdx.x;
    if (idx >= 147456) return;
    int t = idx >> 14;
    int c = (idx >> 12) & 3;
    int oc = (idx >> 5) & 127;
    int kk = idx & 31;
    int ic = c * 32 + kk;
    int ky = t / 3, kx = t - ky * 3;
    float v = fw[((oc * 128 + ic) * 3 + ky) * 3 + kx];
    ushort h = f2bf(v);
    Whi[idx] = h;
    Wlo[idx] = f2bf(v - bf2f(h));
}

// ---------- Kernel C: fuse conv via split-bf16 MFMA + relu + global mean ----
// Block: 256 px (2 rows of 128) x 128 oc; wave = 64 px x 128 oc. B loaded
// per-wave DIRECTLY from global (L2-resident, 1.2 MB total) — no LDS staging,
// no barriers in the K-loop, A-prefetch stays in flight across iterations.
__global__ __launch_bounds__(256, 2) void fuse_mfma(
    const ushort* __restrict__ Ahi, const ushort* __restrict__ Alo,
    const ushort* __restrict__ Whi, const ushort* __restrict__ Wlo,
    const float* __restrict__ bias, float* __restrict__ featsum)
{
    __shared__ float partial[4][128];
    const int ypair = blockIdx.x, b = blockIdx.y;
    const int tid = threadIdx.x, wsub = tid >> 6, lane = tid & 63;
    const int n = lane & 15, q = lane >> 4;
    const int y = ypair * 2 + (wsub >> 1);       // conv row for this wave
    const int xbase = (wsub & 1) * 64;           // wave covers x [xbase,xbase+64)

    f32x4 acc[4][8];
#pragma unroll
    for (int mt = 0; mt < 4; ++mt)
#pragma unroll
        for (int g = 0; g < 8; ++g) acc[mt][g] = (f32x4){0.f, 0.f, 0.f, 0.f};

    const uint4 zero4 = make_uint4(0u, 0u, 0u, 0u);

    auto loadA = [&](int tc, uint4* oh, uint4* ol) {
        int t = tc >> 2, c = tc & 3;
        int ky = t / 3, kx = t - ky * 3;
        int yy = y + ky - 1;
        bool yok = (yy >= 0) & (yy < 128);
#pragma unroll
        for (int mt = 0; mt < 4; ++mt) {
            int xp = xbase + mt * 16 + n + kx - 1;
            bool ok = yok & (xp >= 0) & (xp < 128);
            int yyc = ok ? yy : 0, xpc = ok ? xp : 0;
            size_t aoff = ((size_t)((b * 128 + yyc) * 128 + xpc) << 7) + c * 32 + q * 8;
            oh[mt] = ok ? *(const uint4*)(Ahi + aoff) : zero4;
            ol[mt] = ok ? *(const uint4*)(Alo + aoff) : zero4;
        }
    };

    uint4 pAh[4], pAl[4];
    loadA(0, pAh, pAl);

    // lane-fixed part of the B-fragment address
    const int boff = n * 32 + q * 8;

    for (int tc = 0; tc < 36; ++tc) {
        uint4 cAh[4], cAl[4];
#pragma unroll
        for (int mt = 0; mt < 4; ++mt) { cAh[mt] = pAh[mt]; cAl[mt] = pAl[mt]; }
        if (tc + 1 < 36) loadA(tc + 1, pAh, pAl);
        const ushort* bhp = Whi + tc * 4096 + boff;
        const ushort* blp = Wlo + tc * 4096 + boff;
#pragma unroll
        for (int g = 0; g < 8; ++g) {
            bf16x8 bh = __builtin_bit_cast(bf16x8, *(const uint4*)(bhp + g * 512));
            bf16x8 bl = __builtin_bit_cast(bf16x8, *(const uint4*)(blp + g * 512));
#pragma unroll
            for (int mt = 0; mt < 4; ++mt) {
                bf16x8 ah = __builtin_bit_cast(bf16x8, cAh[mt]);
                bf16x8 al = __builtin_bit_cast(bf16x8, cAl[mt]);
                acc[mt][g] = __builtin_amdgcn_mfma_f32_16x16x32_bf16(ah, bh, acc[mt][g], 0, 0, 0);
                acc[mt][g] = __builtin_amdgcn_mfma_f32_16x16x32_bf16(ah, bl, acc[mt][g], 0, 0, 0);
                acc[mt][g] = __builtin_amdgcn_mfma_f32_16x16x32_bf16(al, bh, acc[mt][g], 0, 0, 0);
            }
        }
    }

    // Epilogue: lane (q,n) of tile (mt,g) holds D[px = q*4+r][oc = g*16+n].
#pragma unroll
    for (int g = 0; g < 8; ++g) {
        float bv = bias[g * 16 + n];
        float v = 0.f;
#pragma unroll
        for (int mt = 0; mt < 4; ++mt)
#pragma unroll
            for (int r = 0; r < 4; ++r) v += fmaxf(acc[mt][g][r] + bv, 0.f);
        v += __shfl_xor(v, 16);
        v += __shfl_xor(v, 32);
        if (lane < 16) partial[wsub][g * 16 + lane] = v;
    }
    __syncthreads();
    if (tid < 128) {
        float v = partial[0][tid] + partial[1][tid] + partial[2][tid] + partial[3][tid];
        atomicAdd(&featsum[b * 128 + tid], v);
    }
}

// ---------- Kernel D: det head + sigmoid + NMS + outputs --------------------
__global__ void det_nms(const float* __restrict__ featsum,
                        const float* __restrict__ dw, const float* __restrict__ db,
                        float* __restrict__ out)
{
    const int b = threadIdx.x;
    if (b >= 8) return;
    const float inv = 1.0f / 16384.0f;

    float p[18];
    for (int j = 0; j < 18; ++j) {
        float a = db[j];
        const float* wp = &dw[j * 128];
        const float* f = &featsum[b * 128];
        for (int c = 0; c < 128; ++c) a = fmaf(wp[c], f[c] * inv, a);
        p[j] = a;
    }
    for (int a = 0; a < 3; ++a)
        for (int e = 0; e < 6; ++e) out[b * 18 + a * 6 + e] = p[a * 6 + e];

    float bx[3][4], sc[3];
    bool ck[3];
    for (int a = 0; a < 3; ++a) {
        for (int k = 0; k < 4; ++k) {
            bx[a][k] = p[a * 6 + k];
            out[144 + b * 12 + a * 4 + k] = bx[a][k];
        }
        float sg = 1.f / (1.f + expf(-p[a * 6 + 4]));
        sc[a] = sg;
        ck[a] = sg > 0.5f;
        out[240 + b * 3 + a] = sg;
    }

    float key[3];
    int order[3];
    bool used[3] = {false, false, false};
    for (int a = 0; a < 3; ++a) key[a] = ck[a] ? sc[a] : -INFINITY;
    for (int i = 0; i < 3; ++i) {
        int best = -1;
        float bk = 0.f;
        for (int a = 0; a < 3; ++a) {
            if (used[a]) continue;
            if (best < 0 || key[a] > bk) { best = a; bk = key[a]; }
        }
        order[i] = best;
        used[best] = true;
    }

    float X1[3], Y1[3], X2[3], Y2[3], AR[3];
    for (int i = 0; i < 3; ++i) {
        int o = order[i];
        X1[i] = bx[o][0]; Y1[i] = bx[o][1];
        X2[i] = bx[o][2]; Y2[i] = bx[o][3];
        AR[i] = (X2[i] - X1[i]) * (Y2[i] - Y1[i]);
    }
    bool suppressed[3] = {false, false, false}, keep_s[3];
    for (int i = 0; i < 3; ++i) {
        bool valid = !suppressed[i];
        keep_s[i] = valid;
        if (valid) {
            for (int j = i + 1; j < 3; ++j) {
                float ix1 = fmaxf(X1[i], X1[j]), iy1 = fmaxf(Y1[i], Y1[j]);
                float ix2 = fminf(X2[i], X2[j]), iy2 = fminf(Y2[i], Y2[j]);
                float inter = fmaxf(ix2 - ix1, 0.f) * fmaxf(iy2 - iy1, 0.f);
                float iou = inter / (AR[i] + AR[j] - inter);
                if (iou > 0.5f) suppressed[j] = true;
            }
        }
    }
    bool keep[3];
    for (int i = 0; i < 3; ++i) keep[order[i]] = keep_s[i];
    for (int a = 0; a < 3; ++a)
        out[264 + b * 3 + a] = (keep[a] && ck[a]) ? 1.f : 0.f;
}

__global__ void zero_feat(float* __restrict__ p)
{
    int i = blockIdx.x * 256 + threadIdx.x;
    if (i < 1024) p[i] = 0.f;
}

// ---------------------------------------------------------------------------
extern "C" void kernel_launch(void* const* d_in, const int* in_sizes, int n_in,
                              void* d_out, int out_size, void* d_ws, size_t ws_size,
                              hipStream_t stream)
{
    const float* x      = (const float*)d_in[0];
    const float* rgb_w1 = (const float*)d_in[1];
    const float* rgb_b1 = (const float*)d_in[2];
    const float* rgb_w2 = (const float*)d_in[3];
    const float* rgb_b2 = (const float*)d_in[4];
    const float* ir_w1  = (const float*)d_in[5];
    const float* ir_b1  = (const float*)d_in[6];
    const float* ir_w2  = (const float*)d_in[7];
    const float* ir_b2  = (const float*)d_in[8];
    const float* fuse_w = (const float*)d_in[9];
    const float* fuse_b = (const float*)d_in[10];
    const float* det_w  = (const float*)d_in[11];
    const float* det_b  = (const float*)d_in[12];
    float* out = (float*)d_out;

    char* ws = (char*)d_ws;
    ushort* C1h  = (ushort*)(ws);                         // 33,554,432 B
    ushort* C1l  = (ushort*)(ws + 33554432);              // 33,554,432 B
    ushort* Whi  = (ushort*)(ws);                         // 294,912 B (post-conv2)
    ushort* Wlo  = (ushort*)(ws + 294912);                // 294,912 B
    float*  feat = (float*)(ws + 589824);                 // 4,096 B
    ushort* Ahi  = (ushort*)(ws + 67108864);              // 33,554,432 B
    ushort* Alo  = (ushort*)(ws + 100663296);             // 33,554,432 B

    dim3 blk(256);
    hipLaunchKernelGGL(conv1_pool, dim3(16, 16, 8), blk, 0, stream, x, rgb_w1, rgb_b1, C1h, C1l);
    hipLaunchKernelGGL(conv2_mfma, dim3(2, 128, 8), blk, 0, stream, C1h, C1l, rgb_w2, rgb_b2, Ahi, Alo, 0);
    hipLaunchKernelGGL(conv1_pool, dim3(16, 16, 8), blk, 0, stream, x, ir_w1, ir_b1, C1h, C1l);
    hipLaunchKernelGGL(conv2_mfma, dim3(2, 128, 8), blk, 0, stream, C1h, C1l, ir_w2, ir_b2, Ahi, Alo, 64);
    hipLaunchKernelGGL(wprep, dim3(576), blk, 0, stream, fuse_w, Whi, Wlo);
    hipLaunchKernelGGL(zero_feat, dim3(4), blk, 0, stream, feat);
    hipLaunchKernelGGL(fuse_mfma, dim3(64, 8), blk, 0, stream, Ahi, Alo, Whi, Wlo, fuse_b, feat);
    hipLaunchKernelGGL(det_nms, dim3(1), dim3(64), 0, stream, feat, det_w, det_b, out);
}